// Round 15
// baseline (1508.738 us; speedup 1.0000x reference)
//
#include <hip/hip_runtime.h>
#include <cmath>

#define L_   2
#define E_   8
#define NH_  16
#define NKV_ 4
#define HD_  64
#define H_   1024
#define I_   1024
#define B_   2
#define S_   1024
#define T_   (B_*S_)
#define V_   32000
#define CAP_ 5120
#define QKVN 1536
#define LD64  72   // LDS row stride (shorts) for BK=64 tiles
#define AST  72    // LDS row stride (shorts) for attention tiles

typedef float f32x4 __attribute__((ext_vector_type(4)));
typedef short s16x4 __attribute__((ext_vector_type(4)));
typedef short s16x8 __attribute__((ext_vector_type(8)));

__device__ __forceinline__ short f2bf(float f) {
    unsigned u = __float_as_uint(f);
    u = (u + 0x7fffu + ((u >> 16) & 1u)) >> 16;   // RNE
    return (short)u;
}
__device__ __forceinline__ float bf2f(short h) {
    return __uint_as_float(((unsigned)(unsigned short)h) << 16);
}
__device__ __forceinline__ s16x8 ldfrag(const short* p) {
    s16x4 lo = *reinterpret_cast<const s16x4*>(p);
    s16x4 hi = *reinterpret_cast<const s16x4*>(p + 16);
    return __builtin_shufflevector(lo, hi, 0, 1, 2, 3, 4, 5, 6, 7);
}

// ---------------- converters ----------------
__global__ __launch_bounds__(256)
void k_cvt(const float* __restrict__ s, short* __restrict__ d, int n8)
{
    const int i = blockIdx.x * 256 + threadIdx.x;
    if (i >= n8) return;
    const float4 a = *reinterpret_cast<const float4*>(s + (size_t)i * 8);
    const float4 b = *reinterpret_cast<const float4*>(s + (size_t)i * 8 + 4);
    s16x8 o;
    o[0]=f2bf(a.x); o[1]=f2bf(a.y); o[2]=f2bf(a.z); o[3]=f2bf(a.w);
    o[4]=f2bf(b.x); o[5]=f2bf(b.y); o[6]=f2bf(b.z); o[7]=f2bf(b.w);
    *reinterpret_cast<s16x8*>(d + (size_t)i * 8) = o;
}

__global__ __launch_bounds__(256)
void k_cvt_sp(const float* __restrict__ s, short* __restrict__ dh, short* __restrict__ dl, int n8)
{
    const int i = blockIdx.x * 256 + threadIdx.x;
    if (i >= n8) return;
    const float4 a = *reinterpret_cast<const float4*>(s + (size_t)i * 8);
    const float4 b = *reinterpret_cast<const float4*>(s + (size_t)i * 8 + 4);
    float v[8] = {a.x, a.y, a.z, a.w, b.x, b.y, b.z, b.w};
    s16x8 oh, ol;
    #pragma unroll
    for (int j = 0; j < 8; j++) {
        const short hh = f2bf(v[j]);
        oh[j] = hh;
        ol[j] = f2bf(v[j] - bf2f(hh));
    }
    *reinterpret_cast<s16x8*>(dh + (size_t)i * 8) = oh;
    *reinterpret_cast<s16x8*>(dl + (size_t)i * 8) = ol;
}

// ---------------- transposing split converter ----------------
__global__ __launch_bounds__(256)
void k_cvt_sp_t(const float* __restrict__ w, short* __restrict__ oh, short* __restrict__ ol,
                int N, int K)
{
    const int n0 = blockIdx.x * 64, k0 = blockIdx.y * 64;
    const int r = threadIdx.x >> 2, c0 = (threadIdx.x & 3) * 16;
    __shared__ float Tt[64][65];
    const float* src = w + (size_t)(k0 + r) * N + n0 + c0;
    #pragma unroll
    for (int g = 0; g < 4; g++) {
        const float4 a = *reinterpret_cast<const float4*>(src + g * 4);
        Tt[c0 + g*4 + 0][r] = a.x; Tt[c0 + g*4 + 1][r] = a.y;
        Tt[c0 + g*4 + 2][r] = a.z; Tt[c0 + g*4 + 3][r] = a.w;
    }
    __syncthreads();
    const size_t o = (size_t)(n0 + r) * K + k0 + c0;
    #pragma unroll
    for (int g = 0; g < 2; g++) {
        s16x8 vh, vl;
        #pragma unroll
        for (int j = 0; j < 8; j++) {
            const float v = Tt[r][c0 + g * 8 + j];
            const short hh = f2bf(v);
            vh[j] = hh; vl[j] = f2bf(v - bf2f(hh));
        }
        *reinterpret_cast<s16x8*>(oh + o + g * 8) = vh;
        *reinterpret_cast<s16x8*>(ol + o + g * 8) = vl;
    }
}

// ---------------- K/V -> split bf16 ----------------
__global__ __launch_bounds__(256)
void k_cvt_kv(const float* __restrict__ qkvp,
              short* __restrict__ khi, short* __restrict__ klo,
              short* __restrict__ vth, short* __restrict__ vtl)
{
    const int blk = blockIdx.x;
    const int s0  = (blk & 15) * 64;
    const int kvh = (blk >> 4) & 3;
    const int b   = blk >> 6;
    const int tid = threadIdx.x;
    const int r = tid >> 2, c0 = (tid & 3) * 16;
    __shared__ float Vt[64][65];

    const float* kp = qkvp + (size_t)(b * S_ + s0 + r) * QKVN + 1024 + kvh * 64 + c0;
    const size_t ko = ((size_t)(b * 4 + kvh) * S_ + s0 + r) * 64 + c0;
    #pragma unroll
    for (int g = 0; g < 2; g++) {
        const float4 a = *reinterpret_cast<const float4*>(kp + g * 8);
        const float4 bq = *reinterpret_cast<const float4*>(kp + g * 8 + 4);
        float v[8] = {a.x, a.y, a.z, a.w, bq.x, bq.y, bq.z, bq.w};
        s16x8 oh, ol;
        #pragma unroll
        for (int j = 0; j < 8; j++) {
            const short hh = f2bf(v[j]);
            oh[j] = hh; ol[j] = f2bf(v[j] - bf2f(hh));
        }
        *reinterpret_cast<s16x8*>(khi + ko + g * 8) = oh;
        *reinterpret_cast<s16x8*>(klo + ko + g * 8) = ol;
    }
    const float* vp = kp + 256;
    #pragma unroll
    for (int g = 0; g < 4; g++) {
        const float4 a = *reinterpret_cast<const float4*>(vp + g * 4);
        Vt[c0 + g*4 + 0][r] = a.x; Vt[c0 + g*4 + 1][r] = a.y;
        Vt[c0 + g*4 + 2][r] = a.z; Vt[c0 + g*4 + 3][r] = a.w;
    }
    __syncthreads();
    const size_t vo = ((size_t)(b * 4 + kvh) * 64 + r) * S_ + s0 + c0;
    #pragma unroll
    for (int g = 0; g < 2; g++) {
        s16x8 oh, ol;
        #pragma unroll
        for (int j = 0; j < 8; j++) {
            const float v = Vt[r][c0 + g * 8 + j];
            const short hh = f2bf(v);
            oh[j] = hh; ol[j] = f2bf(v - bf2f(hh));
        }
        *reinterpret_cast<s16x8*>(vth + vo + g * 8) = oh;
        *reinterpret_cast<s16x8*>(vtl + vo + g * 8) = ol;
    }
}

// ---------------- embedding ----------------
__global__ void k_embed(const int* __restrict__ ids, const float* __restrict__ emb,
                        float* __restrict__ x)
{
    const int t = blockIdx.x;
    const float* src = emb + (size_t)ids[t] * H_;
    float* dst = x + (size_t)t * H_;
    for (int i = threadIdx.x; i < H_; i += 256) dst[i] = src[i];
}

// ---------------- layernorm (OMODE 0: f32 | 1: +bf16 | 2: +hi/lo split) ----------------
template<int OMODE>
__global__ __launch_bounds__(256)
void k_layernorm(const float* __restrict__ x, const float* __restrict__ g,
                 const float* __restrict__ bb, float* __restrict__ out,
                 short* __restrict__ oh, short* __restrict__ ol)
{
    const int t = blockIdx.x;
    const float* row = x + (size_t)t * H_;
    float s = 0.f, ss = 0.f;
    for (int i = threadIdx.x; i < H_; i += 256) { const float v = row[i]; s += v; ss += v * v; }
    #pragma unroll
    for (int off = 32; off > 0; off >>= 1) {
        s  += __shfl_down(s, off, 64);
        ss += __shfl_down(ss, off, 64);
    }
    __shared__ float shs[4], shss[4];
    const int w = threadIdx.x >> 6;
    if ((threadIdx.x & 63) == 0) { shs[w] = s; shss[w] = ss; }
    __syncthreads();
    const float fs  = shs[0] + shs[1] + shs[2] + shs[3];
    const float fss = shss[0] + shss[1] + shss[2] + shss[3];
    const float mean = fs * (1.f / H_);
    const float var  = fss * (1.f / H_) - mean * mean;
    const float rstd = 1.0f / sqrtf(var + 1e-5f);
    float* orow = out + (size_t)t * H_;
    for (int i = threadIdx.x; i < H_; i += 256) {
        const float v = (row[i] - mean) * rstd * g[i] + bb[i];
        orow[i] = v;
        if (OMODE == 1) {
            oh[(size_t)t * H_ + i] = f2bf(v);
        } else if (OMODE == 2) {
            const short hh = f2bf(v);
            oh[(size_t)t * H_ + i] = hh;
            ol[(size_t)t * H_ + i] = f2bf(v - bf2f(hh));
        }
    }
}

// ---------------- fused RoPE: q (16 heads) + k (4 heads) ----------------
__global__ void k_rope_all(float* __restrict__ x)
{
    const int idx  = blockIdx.x * 256 + threadIdx.x;
    const int i    = idx & 31;
    const int rest = idx >> 5;
    const int head = rest % 20;
    const int t    = rest / 20;
    const int pos  = t & (S_ - 1);
    const float p32  = (float)pow(1.0e6, (double)i / 32.0);
    const float invf = 1.0f / p32;
    const float ang  = (float)pos * invf;
    const float c = (float)cos((double)ang);
    const float s = (float)sin((double)ang);
    const int off = (head < 16) ? head * 64 : 1024 + (head - 16) * 64;
    float* base = x + (size_t)t * QKVN + off;
    const float x1 = base[i];
    const float x2 = base[i + 32];
    base[i]      = x1 * c - x2 * s;
    base[i + 32] = x2 * c + x1 * s;
}

// ---------------- split-bf16 MFMA flash attention ----------------
__global__ __launch_bounds__(256)
void k_attn_mfma(const float* __restrict__ q,
                 const short* __restrict__ khi, const short* __restrict__ klo,
                 const short* __restrict__ vth, const short* __restrict__ vtl,
                 short* __restrict__ obh, short* __restrict__ obl)
{
    const int q0 = blockIdx.x * 64, h = blockIdx.y, b = blockIdx.z;
    const int kvh = h >> 2;
    const int tid = threadIdx.x, lane = tid & 63, w = tid >> 6;
    const int fr = lane & 15, fg = lane >> 4;

    __shared__ short Qh[64 * AST], Ql[64 * AST];
    __shared__ short Kh[64 * AST], Kl[64 * AST];
    __shared__ short Vh[64 * AST], Vl[64 * AST];
    __shared__ short Ph[64 * AST], Pl[64 * AST];

    {
        const int r = tid >> 2, c0 = (tid & 3) * 16;
        const float* qs = q + (size_t)(b * S_ + q0 + r) * QKVN + h * HD_ + c0;
        #pragma unroll
        for (int g = 0; g < 2; g++) {
            const float4 a = *reinterpret_cast<const float4*>(qs + g * 8);
            const float4 bq = *reinterpret_cast<const float4*>(qs + g * 8 + 4);
            float v[8] = {a.x, a.y, a.z, a.w, bq.x, bq.y, bq.z, bq.w};
            s16x8 oh, ol;
            #pragma unroll
            for (int j = 0; j < 8; j++) {
                const float sv = v[j] * 0.125f;
                const short hh = f2bf(sv);
                oh[j] = hh; ol[j] = f2bf(sv - bf2f(hh));
            }
            *reinterpret_cast<s16x8*>(&Qh[r * AST + c0 + g * 8]) = oh;
            *reinterpret_cast<s16x8*>(&Ql[r * AST + c0 + g * 8]) = ol;
        }
    }

    f32x4 accO[4];
    #pragma unroll
    for (int n = 0; n < 4; n++) accO[n] = (f32x4){0.f, 0.f, 0.f, 0.f};
    float rs[4] = {0.f, 0.f, 0.f, 0.f};

    const size_t kbase = (size_t)(b * 4 + kvh) * S_ * 64;
    const size_t vbase = (size_t)(b * 4 + kvh) * 64 * S_;
    const int nkb = (q0 >> 6) + 1;

    for (int kb = 0; kb < nkb; kb++) {
        const int j0 = kb * 64;
        __syncthreads();
        {
            const int r = tid >> 2, c0 = (tid & 3) * 16;
            const short* ks = khi + kbase + (size_t)(j0 + r) * 64 + c0;
            const short* ls = klo + kbase + (size_t)(j0 + r) * 64 + c0;
            *reinterpret_cast<s16x8*>(&Kh[r * AST + c0])     = *reinterpret_cast<const s16x8*>(ks);
            *reinterpret_cast<s16x8*>(&Kh[r * AST + c0 + 8]) = *reinterpret_cast<const s16x8*>(ks + 8);
            *reinterpret_cast<s16x8*>(&Kl[r * AST + c0])     = *reinterpret_cast<const s16x8*>(ls);
            *reinterpret_cast<s16x8*>(&Kl[r * AST + c0 + 8]) = *reinterpret_cast<const s16x8*>(ls + 8);
            const short* vs = vth + vbase + (size_t)r * S_ + j0 + c0;
            const short* vl = vtl + vbase + (size_t)r * S_ + j0 + c0;
            *reinterpret_cast<s16x8*>(&Vh[r * AST + c0])     = *reinterpret_cast<const s16x8*>(vs);
            *reinterpret_cast<s16x8*>(&Vh[r * AST + c0 + 8]) = *reinterpret_cast<const s16x8*>(vs + 8);
            *reinterpret_cast<s16x8*>(&Vl[r * AST + c0])     = *reinterpret_cast<const s16x8*>(vl);
            *reinterpret_cast<s16x8*>(&Vl[r * AST + c0 + 8]) = *reinterpret_cast<const s16x8*>(vl + 8);
        }
        __syncthreads();

        f32x4 accS[4];
        #pragma unroll
        for (int n = 0; n < 4; n++) accS[n] = (f32x4){0.f, 0.f, 0.f, 0.f};
        #pragma unroll
        for (int ks2 = 0; ks2 < 2; ks2++) {
            const int ko = ks2 * 32 + fg * 4;
            const s16x8 ah = ldfrag(&Qh[(w * 16 + fr) * AST + ko]);
            const s16x8 al = ldfrag(&Ql[(w * 16 + fr) * AST + ko]);
            #pragma unroll
            for (int n = 0; n < 4; n++) {
                const int base = (n * 16 + fr) * AST + ko;
                const s16x8 bh = ldfrag(&Kh[base]);
                const s16x8 bl = ldfrag(&Kl[base]);
                accS[n] = __builtin_amdgcn_mfma_f32_16x16x32_bf16(ah, bh, accS[n], 0, 0, 0);
                accS[n] = __builtin_amdgcn_mfma_f32_16x16x32_bf16(al, bh, accS[n], 0, 0, 0);
                accS[n] = __builtin_amdgcn_mfma_f32_16x16x32_bf16(ah, bl, accS[n], 0, 0, 0);
            }
        }

        #pragma unroll
        for (int r = 0; r < 4; r++) {
            const int qrow = q0 + w * 16 + fg * 4 + r;
            float ev[4];
            float p = 0.f;
            #pragma unroll
            for (int n = 0; n < 4; n++) {
                const int key = j0 + n * 16 + fr;
                const float e = (key <= qrow) ? expf(accS[n][r]) : 0.f;
                ev[n] = e; p += e;
            }
            p += __shfl_xor(p, 1, 64); p += __shfl_xor(p, 2, 64);
            p += __shfl_xor(p, 4, 64); p += __shfl_xor(p, 8, 64);
            rs[r] += p;
            #pragma unroll
            for (int n = 0; n < 4; n++) {
                const int addr = (w * 16 + fg * 4 + r) * AST + n * 16 + fr;
                const short hh = f2bf(ev[n]);
                Ph[addr] = hh;
                Pl[addr] = f2bf(ev[n] - bf2f(hh));
            }
        }
        __builtin_amdgcn_wave_barrier();

        #pragma unroll
        for (int ks2 = 0; ks2 < 2; ks2++) {
            const int ko = ks2 * 32 + fg * 4;
            const s16x8 ph = ldfrag(&Ph[(w * 16 + fr) * AST + ko]);
            const s16x8 pl = ldfrag(&Pl[(w * 16 + fr) * AST + ko]);
            #pragma unroll
            for (int n = 0; n < 4; n++) {
                const int base = (n * 16 + fr) * AST + ko;
                const s16x8 vh = ldfrag(&Vh[base]);
                const s16x8 vl = ldfrag(&Vl[base]);
                accO[n] = __builtin_amdgcn_mfma_f32_16x16x32_bf16(ph, vh, accO[n], 0, 0, 0);
                accO[n] = __builtin_amdgcn_mfma_f32_16x16x32_bf16(pl, vh, accO[n], 0, 0, 0);
                accO[n] = __builtin_amdgcn_mfma_f32_16x16x32_bf16(ph, vl, accO[n], 0, 0, 0);
            }
        }
    }

    #pragma unroll
    for (int r = 0; r < 4; r++) {
        const float inv = 1.0f / rs[r];
        const int qrow = q0 + w * 16 + fg * 4 + r;
        const size_t ob = (size_t)(b * S_ + qrow) * H_ + h * HD_;
        #pragma unroll
        for (int n = 0; n < 4; n++) {
            const float v = accO[n][r] * inv;
            const short hh = f2bf(v);
            obh[ob + n * 16 + fr] = hh;
            obl[ob + n * 16 + fr] = f2bf(v - bf2f(hh));
        }
    }
}

// ---------------- MoE gate ----------------
__global__ __launch_bounds__(64)
void k_gate(const float* __restrict__ h, const float* __restrict__ gwt, float* __restrict__ w)
{
    const int t = blockIdx.x;
    const int lane = threadIdx.x;
    const float* row = h + (size_t)t * H_;
    float acc[E_];
    #pragma unroll
    for (int e = 0; e < E_; e++) acc[e] = 0.f;
    for (int i = lane; i < H_; i += 64) {
        const float xv = row[i];
        #pragma unroll
        for (int e = 0; e < E_; e++) acc[e] += xv * gwt[(size_t)e * H_ + i];
    }
    #pragma unroll
    for (int e = 0; e < E_; e++) {
        #pragma unroll
        for (int off = 32; off > 0; off >>= 1) acc[e] += __shfl_down(acc[e], off, 64);
    }
    if (lane == 0) {
        int i1 = 0; float m1 = acc[0];
        #pragma unroll
        for (int e = 1; e < E_; e++) if (acc[e] > m1) { m1 = acc[e]; i1 = e; }
        int i2 = -1; float m2 = -1e30f;
        #pragma unroll
        for (int e = 0; e < E_; e++) if (e != i1 && acc[e] > m2) { m2 = acc[e]; i2 = e; }
        const float e2  = expf(m2 - m1);
        const float den = 1.0f + e2;
        #pragma unroll
        for (int e = 0; e < E_; e++)
            w[t * E_ + e] = (e == i1) ? (1.0f / den) : ((e == i2) ? (e2 / den) : 0.f);
    }
}

// ---------------- build per-expert token lists ----------------
__global__ __launch_bounds__(512)
void k_build(const float* __restrict__ gw, int* __restrict__ idx, float* __restrict__ wl,
             int* __restrict__ pos, int* __restrict__ cnt, int* __restrict__ seg)
{
    const int e = threadIdx.x >> 6;
    const int lane = threadIdx.x & 63;
    __shared__ int scnt[E_], sseg[E_];
    int c = 0;
    for (int t0 = 0; t0 < T_; t0 += 64) {
        const float v = gw[(size_t)(t0 + lane) * E_ + e];
        c += __popcll(__ballot(v > 0.f));
    }
    if (lane == 0) scnt[e] = c;
    __syncthreads();
    if (threadIdx.x == 0) {
        int off = 0;
        for (int q = 0; q < E_; q++) {
            sseg[q] = off; cnt[q] = scnt[q]; seg[q] = off;
            off += (scnt[q] + 127) & ~127;
        }
    }
    __syncthreads();
    int p = sseg[e];
    for (int t0 = 0; t0 < T_; t0 += 64) {
        const int t = t0 + lane;
        const float v = gw[(size_t)t * E_ + e];
        const unsigned long long m = __ballot(v > 0.f);
        if (v > 0.f) {
            const int pp = p + __popcll(m & ((1ull << lane) - 1ull));
            idx[pp] = t; wl[pp] = v;
            int slot = 0;
            for (int q = 0; q < e; q++) slot += (gw[(size_t)t * E_ + q] > 0.f) ? 1 : 0;
            pos[t * 2 + slot] = pp;
        }
        p += __popcll(m);
    }
}

// ---------------- combine ----------------
__global__ void k_combine(float* __restrict__ x, const float* __restrict__ ebuf,
                          const float* __restrict__ wl, const int* __restrict__ pos)
{
    const int id = blockIdx.x * 256 + threadIdx.x;
    const int t = id >> 10;
    const int hc = id & 1023;
    const int p0 = pos[t * 2], p1 = pos[t * 2 + 1];
    x[id] += wl[p0] * ebuf[(size_t)p0 * H_ + hc] + wl[p1] * ebuf[(size_t)p1 * H_ + hc];
}

// ---------------- silu combines ----------------
__global__ __launch_bounds__(256)
void k_silu_sp(const float* __restrict__ g, short* __restrict__ uh, short* __restrict__ ul)
{
    const size_t i = (size_t)blockIdx.x * 256 + threadIdx.x;
    const float gv = g[i];
    const float u = bf2f(uh[i]) + bf2f(ul[i]);
    const float p = gv * (1.f / (1.f + expf(-gv))) * u;
    const short hh = f2bf(p);
    uh[i] = hh;
    ul[i] = f2bf(p - bf2f(hh));
}

__global__ __launch_bounds__(256)
void k_silu_b(const float* __restrict__ g, short* __restrict__ ub)
{
    const size_t i = (size_t)blockIdx.x * 256 + threadIdx.x;
    const float gv = g[i];
    const float p = gv * (1.f / (1.f + expf(-gv))) * bf2f(ub[i]);
    ub[i] = f2bf(p);
}

// ---------------- bf16-input MFMA GEMM, BK=64 dbuf 1-barrier (lm_head), XCD-swizzled ----------------
__global__ __launch_bounds__(256)
void k_mfma_bt64(const short* __restrict__ A, const short* __restrict__ Bm,
                 float* __restrict__ C, int M, int N, int K)
{
    __shared__ short Als[2][128 * LD64];
    __shared__ short Bls[2][128 * LD64];
    const int mB = M >> 7;
    const int nwg = mB * (N >> 7);
    int l = blockIdx.x;
    l = (l & 7) * (nwg >> 3) + (l >> 3);     // bijective XCD swizzle (nwg % 8 == 0)
    const int g  = l / (mB * 8);
    const int ii = l - g * (mB * 8);
    const int bm0 = (ii % mB) * 128;
    const int bn0 = (g * 8 + ii / mB) * 128;

    const int tid  = threadIdx.x;
    const int lane = tid & 63, w = tid >> 6;
    const int wr = w >> 1, wc = w & 1;
    const int fr = lane & 15, fg = lane >> 4;
    const int srow = tid >> 1, sk = (tid & 1) * 32;

    const short* pa = A  + (size_t)(bm0 + srow) * K + sk;
    const short* pb = Bm + (size_t)(bn0 + srow) * K + sk;

    f32x4 acc[4][4];
    #pragma unroll
    for (int m = 0; m < 4; m++)
        #pragma unroll
        for (int n = 0; n < 4; n++) acc[m][n] = (f32x4){0.f, 0.f, 0.f, 0.f};

    s16x8 ra[4], rb[4];
    #pragma unroll
    for (int q = 0; q < 4; q++) {
        ra[q] = *reinterpret_cast<const s16x8*>(pa + q * 8);
        rb[q] = *reinterpret_cast<const s16x8*>(pb + q * 8);
    }
    #pragma unroll
    for (int q = 0; q < 4; q++) {
        *reinterpret_cast<s16x8*>(&Als[0][srow * LD64 + sk + q * 8]) = ra[q];
        *reinterpret_cast<s16x8*>(&Bls[0][srow * LD64 + sk + q * 8]) = rb[q];
    }

    int cur = 0;
    for (int k0 = 0; k0 < K; k0 += 64) {
        if (k0 + 64 < K) {
            #pragma unroll
            for (int q = 0; q < 4; q++) {
                ra[q] = *reinterpret_cast<const s16x8*>(pa + k0 + 64 + q * 8);
                rb[q] = *reinterpret_cast<const s16x8*>(pb + k0 + 64 + q * 8);
            }
        }
        __syncthreads();
        #pragma unroll
        for (int ks2 = 0; ks2 < 2; ks2++) {
            const int ko = ks2 * 32 + fg * 4;
            s16x8 af[4], bfv[4];
            #pragma unroll
            for (int m = 0; m < 4; m++)
                af[m] = ldfrag(&Als[cur][(wr * 64 + m * 16 + fr) * LD64 + ko]);
            #pragma unroll
            for (int n = 0; n < 4; n++)
                bfv[n] = ldfrag(&Bls[cur][(wc * 64 + n * 16 + fr) * LD64 + ko]);
            #pragma unroll
            for (int m = 0; m < 4; m++)
                #pragma unroll
                for (int n = 0; n < 4; n++)
                    acc[m][n] = __builtin_amdgcn_mfma_f32_16x16x32_bf16(af[m], bfv[n], acc[m][n], 0, 0, 0);
        }
        if (k0 + 64 < K) {
            #pragma unroll
            for (int q = 0; q < 4; q++) {
                *reinterpret_cast<s16x8*>(&Als[cur ^ 1][srow * LD64 + sk + q * 8]) = ra[q];
                *reinterpret_cast<s16x8*>(&Bls[cur ^ 1][srow * LD64 + sk + q * 8]) = rb[q];
            }
        }
        cur ^= 1;
    }

    #pragma unroll
    for (int m = 0; m < 4; m++)
        #pragma unroll
        for (int n = 0; n < 4; n++)
            #pragma unroll
            for (int r = 0; r < 4; r++) {
                const int row = bm0 + wr * 64 + m * 16 + fg * 4 + r;
                const int col = bn0 + wc * 64 + n * 16 + fr;
                C[(size_t)row * N + col] = acc[m][n][r];
            }
}

// ---------------- bf16-input MFMA MoE GEMM, BK=64 dbuf (L2; sd/wd) ----------------
template<int MODE, int EPI>
__global__ __launch_bounds__(256)
void k_mfma_moe64(const short* __restrict__ A, const short* __restrict__ Bm,
                  float* __restrict__ Cf,
                  const int* __restrict__ idx, const int* __restrict__ cnt,
                  const int* __restrict__ seg, int N, int K)
{
    int c = T_, s = 0;
    const int bm0 = blockIdx.y * 128, bn0 = blockIdx.x * 128;
    if (MODE >= 1) {
        const int e = blockIdx.z;
        c = cnt[e];
        if (bm0 >= c) return;
        s = seg[e];
        Bm += (size_t)e * N * K;
    }
    __shared__ short Als[2][128 * LD64];
    __shared__ short Bls[2][128 * LD64];
    const int tid  = threadIdx.x;
    const int lane = tid & 63, w = tid >> 6;
    const int wr = w >> 1, wc = w & 1;
    const int fr = lane & 15, fg = lane >> 4;
    const int srow = tid >> 1, sk = (tid & 1) * 32;

    int arow;
    if (MODE == 0)      arow = bm0 + srow;
    else if (MODE == 1) arow = idx[s + min(bm0 + srow, c - 1)];
    else                arow = s + min(bm0 + srow, c - 1);
    const short* pa = A  + (size_t)arow * K + sk;
    const short* pb = Bm + (size_t)(bn0 + srow) * K + sk;

    f32x4 acc[4][4];
    #pragma unroll
    for (int m = 0; m < 4; m++)
        #pragma unroll
        for (int n = 0; n < 4; n++) acc[m][n] = (f32x4){0.f, 0.f, 0.f, 0.f};

    s16x8 ra[4], rb[4];
    #pragma unroll
    for (int q = 0; q < 4; q++) {
        ra[q] = *reinterpret_cast<const s16x8*>(pa + q * 8);
        rb[q] = *reinterpret_cast<const s16x8*>(pb + q * 8);
    }
    #pragma unroll
    for (int q = 0; q < 4; q++) {
        *reinterpret_cast<s16x8*>(&Als[0][srow * LD64 + sk + q * 8]) = ra[q];
        *reinterpret_cast<s16x8*>(&Bls[0][srow * LD64 + sk + q * 8]) = rb[q];
    }

    int cur = 0;
    for (int k0 = 0; k0 < K; k0 += 64) {
        if (k0 + 64 < K) {
            #pragma unroll
            for (int q = 0; q < 4; q++) {
                ra[q] = *reinterpret_cast<const s16x8*>(pa + k0 + 64 + q * 8);
                rb[q] = *reinterpret_cast<const s16x8*>(pb + k0 + 64 + q * 8);
            }
        }
        __syncthreads();
        #pragma unroll
        for (int ks2 = 0; ks2 < 2; ks2++) {
            const int ko = ks2 * 32 + fg * 4;
            s16x8 af[4], bfv[4];
            #pragma unroll
            for (int m = 0; m < 4; m++)
                af[m] = ldfrag(&Als[cur][(wr * 64 + m * 16 + fr) * LD64 + ko]);
            #pragma unroll
            for (int n = 0; n < 4; n++)
                bfv[n] = ldfrag(&Bls[cur][(wc * 64 + n * 16 + fr) * LD64 + ko]);
            #pragma unroll
            for (int m = 0; m < 4; m++)
                #pragma unroll
                for (int n = 0; n < 4; n++)
                    acc[m][n] = __builtin_amdgcn_mfma_f32_16x16x32_bf16(af[m], bfv[n], acc[m][n], 0, 0, 0);
        }
        if (k0 + 64 < K) {
            #pragma unroll
            for (int q = 0; q < 4; q++) {
                *reinterpret_cast<s16x8*>(&Als[cur ^ 1][srow * LD64 + sk + q * 8]) = ra[q];
                *reinterpret_cast<s16x8*>(&Bls[cur ^ 1][srow * LD64 + sk + q * 8]) = rb[q];
            }
        }
        cur ^= 1;
    }

    #pragma unroll
    for (int m = 0; m < 4; m++)
        #pragma unroll
        for (int n = 0; n < 4; n++)
            #pragma unroll
            for (int r = 0; r < 4; r++) {
                const int row = bm0 + wr * 64 + m * 16 + fg * 4 + r;
                if (MODE >= 1 && row >= c) continue;
                const int col = bn0 + wc * 64 + n * 16 + fr;
                const size_t p = (size_t)((MODE >= 1 ? s : 0) + row) * N + col;
                if (EPI == 0) Cf[p] = acc[m][n][r];
                else          Cf[p] += acc[m][n][r];
            }
}

// ---------------- plain bf16 fused wg|wu GEMM, BK=64 dbuf (L2) ----------------
template<int MODE>
__global__ __launch_bounds__(256)
void k_mfma_b_gu64(const short* __restrict__ A, const short* __restrict__ Bg,
                   const short* __restrict__ Bu, float* __restrict__ Cg,
                   short* __restrict__ Cu,
                   const int* __restrict__ idx, const int* __restrict__ cnt,
                   const int* __restrict__ seg, int K)
{
    int c = T_, s = 0;
    const int bm0 = blockIdx.y * 128;
    const int bn0all = blockIdx.x * 128;
    if (MODE >= 1) {
        const int e = blockIdx.z;
        c = cnt[e];
        if (bm0 >= c) return;
        s = seg[e];
        Bg += (size_t)e * I_ * K;
        Bu += (size_t)e * I_ * K;
    }
    const int isU = (bn0all >= I_) ? 1 : 0;
    const int bn0 = bn0all - isU * I_;
    const short* Bm = isU ? Bu : Bg;

    __shared__ short Als[2][128 * LD64];
    __shared__ short Bls[2][128 * LD64];
    const int tid  = threadIdx.x;
    const int lane = tid & 63, w = tid >> 6;
    const int wr = w >> 1, wc = w & 1;
    const int fr = lane & 15, fg = lane >> 4;
    const int srow = tid >> 1, sk = (tid & 1) * 32;

    int arow;
    if (MODE == 0) arow = bm0 + srow;
    else           arow = idx[s + min(bm0 + srow, c - 1)];
    const short* pa = A  + (size_t)arow * K + sk;
    const short* pb = Bm + (size_t)(bn0 + srow) * K + sk;

    f32x4 acc[4][4];
    #pragma unroll
    for (int m = 0; m < 4; m++)
        #pragma unroll
        for (int n = 0; n < 4; n++) acc[m][n] = (f32x4){0.f, 0.f, 0.f, 0.f};

    s16x8 ra[4], rb[4];
    #pragma unroll
    for (int q = 0; q < 4; q++) {
        ra[q] = *reinterpret_cast<const s16x8*>(pa + q * 8);
        rb[q] = *reinterpret_cast<const s16x8*>(pb + q * 8);
    }
    #pragma unroll
    for (int q = 0; q < 4; q++) {
        *reinterpret_cast<s16x8*>(&Als[0][srow * LD64 + sk + q * 8]) = ra[q];
        *reinterpret_cast<s16x8*>(&Bls[0][srow * LD64 + sk + q * 8]) = rb[q];
    }

    int cur = 0;
    for (int k0 = 0; k0 < K; k0 += 64) {
        if (k0 + 64 < K) {
            #pragma unroll
            for (int q = 0; q < 4; q++) {
                ra[q] = *reinterpret_cast<const s16x8*>(pa + k0 + 64 + q * 8);
                rb[q] = *reinterpret_cast<const s16x8*>(pb + k0 + 64 + q * 8);
            }
        }
        __syncthreads();
        #pragma unroll
        for (int ks2 = 0; ks2 < 2; ks2++) {
            const int ko = ks2 * 32 + fg * 4;
            s16x8 af[4], bfv[4];
            #pragma unroll
            for (int m = 0; m < 4; m++)
                af[m] = ldfrag(&Als[cur][(wr * 64 + m * 16 + fr) * LD64 + ko]);
            #pragma unroll
            for (int n = 0; n < 4; n++)
                bfv[n] = ldfrag(&Bls[cur][(wc * 64 + n * 16 + fr) * LD64 + ko]);
            #pragma unroll
            for (int m = 0; m < 4; m++)
                #pragma unroll
                for (int n = 0; n < 4; n++)
                    acc[m][n] = __builtin_amdgcn_mfma_f32_16x16x32_bf16(af[m], bfv[n], acc[m][n], 0, 0, 0);
        }
        if (k0 + 64 < K) {
            #pragma unroll
            for (int q = 0; q < 4; q++) {
                *reinterpret_cast<s16x8*>(&Als[cur ^ 1][srow * LD64 + sk + q * 8]) = ra[q];
                *reinterpret_cast<s16x8*>(&Bls[cur ^ 1][srow * LD64 + sk + q * 8]) = rb[q];
            }
        }
        cur ^= 1;
    }

    #pragma unroll
    for (int m = 0; m < 4; m++)
        #pragma unroll
        for (int n = 0; n < 4; n++)
            #pragma unroll
            for (int r = 0; r < 4; r++) {
                const int row = bm0 + wr * 64 + m * 16 + fg * 4 + r;
                if (MODE >= 1 && row >= c) continue;
                const int col = bn0 + wc * 64 + n * 16 + fr;
                const size_t p = (size_t)((MODE >= 1 ? s : 0) + row) * I_ + col;
                if (!isU) Cg[p] = acc[m][n][r];
                else      Cu[p] = f2bf(acc[m][n][r]);
            }
}

// ---------------- split-bf16 MFMA GEMM, BK=64 (routing-safe; qkv/wo/sd/wd) ----------------
// EPI 0: store f32 | 2: += f32
template<int MODE, int EPI>
__global__ __launch_bounds__(256)
void k_mfma_sp64(const short* __restrict__ Ah, const short* __restrict__ Alp,
                 const short* __restrict__ Bh, const short* __restrict__ Blp,
                 float* __restrict__ Cf,
                 const int* __restrict__ idx, const int* __restrict__ cnt,
                 const int* __restrict__ seg, int N, int K)
{
    int c = T_, s = 0;
    const int bm0 = blockIdx.y * 128, bn0 = blockIdx.x * 128;
    if (MODE >= 1) {
        const int e = blockIdx.z;
        c = cnt[e];
        if (bm0 >= c) return;
        s = seg[e];
        Bh  += (size_t)e * N * K;
        Blp += (size_t)e * N * K;
    }
    __shared__ short LAh[128 * LD64];
    __shared__ short LAl[128 * LD64];
    __shared__ short LBh[128 * LD64];
    __shared__ short LBl[128 * LD64];
    const int tid  = threadIdx.x;
    const int lane = tid & 63, w = tid >> 6;
    const int wr = w >> 1, wc = w & 1;
    const int fr = lane & 15, fg = lane >> 4;
    const int srow = tid >> 1, sk = (tid & 1) * 32;

    int arow;
    if (MODE == 0)      arow = bm0 + srow;
    else if (MODE == 1) arow = idx[s + min(bm0 + srow, c - 1)];
    else                arow = s + min(bm0 + srow, c - 1);
    const short* pah = Ah  + (size_t)arow * K + sk;
    const short* pal = Alp + (size_t)arow * K + sk;
    const short* pbh = Bh  + (size_t)(bn0 + srow) * K + sk;
    const short* pbl = Blp + (size_t)(bn0 + srow) * K + sk;

    f32x4 acc[4][4];
    #pragma unroll
    for (int m = 0; m < 4; m++)
        #pragma unroll
        for (int n = 0; n < 4; n++) acc[m][n] = (f32x4){0.f, 0.f, 0.f, 0.f};

    s16x8 rah[4], ral[4], rbh[4], rbl[4];
    #pragma unroll
    for (int q = 0; q < 4; q++) {
        rah[q] = *reinterpret_cast<const s16x8*>(pah + q * 8);
        ral[q] = *reinterpret_cast<const s16x8*>(pal + q * 8);
        rbh[q] = *reinterpret_cast<const s16x8*>(pbh + q * 8);
        rbl[q] = *reinterpret_cast<const s16x8*>(pbl + q * 8);
    }

    for (int k0 = 0; k0 < K; k0 += 64) {
        __syncthreads();
        #pragma unroll
        for (int q = 0; q < 4; q++) {
            *reinterpret_cast<s16x8*>(&LAh[srow * LD64 + sk + q * 8]) = rah[q];
            *reinterpret_cast<s16x8*>(&LAl[srow * LD64 + sk + q * 8]) = ral[q];
            *reinterpret_cast<s16x8*>(&LBh[srow * LD64 + sk + q * 8]) = rbh[q];
            *reinterpret_cast<s16x8*>(&LBl[srow * LD64 + sk + q * 8]) = rbl[q];
        }
        __syncthreads();
        if (k0 + 64 < K) {
            #pragma unroll
            for (int q = 0; q < 4; q++) {
                rah[q] = *reinterpret_cast<const s16x8*>(pah + k0 + 64 + q * 8);
                ral[q] = *reinterpret_cast<const s16x8*>(pal + k0 + 64 + q * 8);
                rbh[q] = *reinterpret_cast<const s16x8*>(pbh + k0 + 64 + q * 8);
                rbl[q] = *reinterpret_cast<const s16x8*>(pbl + k0 + 64 + q * 8);
            }
        }
        #pragma unroll
        for (int ks2 = 0; ks2 < 2; ks2++) {
            const int ko = ks2 * 32 + fg * 4;
            s16x8 afh[4], afl[4];
            #pragma unroll
            for (int m = 0; m < 4; m++) {
                afh[m] = ldfrag(&LAh[(wr * 64 + m * 16 + fr) * LD64 + ko]);
                afl[m] = ldfrag(&LAl[(wr * 64 + m * 16 + fr) * LD64 + ko]);
            }
            #pragma unroll
            for (int n = 0; n < 4; n++) {
                const s16x8 bh = ldfrag(&LBh[(wc * 64 + n * 16 + fr) * LD64 + ko]);
                const s16x8 bl = ldfrag(&LBl[(wc * 64 + n * 16 + fr) * LD64 + ko]);
                #pragma unroll
                for (int m = 0; m < 4; m++) {
                    acc[m][n] = __builtin_amdgcn_mfma_f32_16x16x32_bf16(afh[m], bh, acc[m][n], 0, 0, 0);
                    acc[m][n] = __builtin_amdgcn_mfma_f32_16x16x32_bf16(afl[m], bh, acc[m][n], 0, 0, 0);
                    acc[m][n] = __builtin_amdgcn_mfma_f32_16x16x32_bf16(afh[m], bl, acc[m][n], 0, 0, 0);
                }
            }
        }
    }

    #pragma unroll
    for (int m = 0; m < 4; m++)
        #pragma unroll
        for (int n = 0; n < 4; n++)
            #pragma unroll
            for (int r = 0; r < 4; r++) {
                const int row = bm0 + wr * 64 + m * 16 + fg * 4 + r;
                if (MODE >= 1 && row >= c) continue;
                const int col = bn0 + wc * 64 + n * 16 + fr;
                const size_t p = (size_t)((MODE >= 1 ? s : 0) + row) * N + col;
                if (EPI == 0) Cf[p] = acc[m][n][r];
                else          Cf[p] += acc[m][n][r];
            }
}

// ---------------- split-bf16 fused wg|wu GEMM, BK=64 (L1) ----------------
template<int MODE>
__global__ __launch_bounds__(256)
void k_mfma_sp_gu64(const short* __restrict__ Ah, const short* __restrict__ Alp,
                    const short* __restrict__ Bgh, const short* __restrict__ Bgl,
                    const short* __restrict__ Buh, const short* __restrict__ Bul,
                    float* __restrict__ Cg, short* __restrict__ Cuh, short* __restrict__ Cul,
                    const int* __restrict__ idx, const int* __restrict__ cnt,
                    const int* __restrict__ seg, int K)
{
    int c = T_, s = 0;
    const int bm0 = blockIdx.y * 128;
    const int bn0all = blockIdx.x * 128;
    if (MODE >= 1) {
        const int e = blockIdx.z;
        c = cnt[e];
        if (bm0 >= c) return;
        s = seg[e];
        Bgh += (size_t)e * I_ * K; Bgl += (size_t)e * I_ * K;
        Buh += (size_t)e * I_ * K; Bul += (size_t)e * I_ * K;
    }
    const int isU = (bn0all >= I_) ? 1 : 0;
    const int bn0 = bn0all - isU * I_;
    const short* Bh  = isU ? Buh : Bgh;
    const short* Blp = isU ? Bul : Bgl;

    __shared__ short LAh[128 * LD64];
    __shared__ short LAl[128 * LD64];
    __shared__ short LBh[128 * LD64];
    __shared__ short LBl[128 * LD64];
    const int tid  = threadIdx.x;
    const int lane = tid & 63, w = tid >> 6;
    const int wr = w >> 1, wc = w & 1;
    const int fr = lane & 15, fg = lane >> 4;
    const int srow = tid >> 1, sk = (tid & 1) * 32;

    int arow;
    if (MODE == 0) arow = bm0 + srow;
    else           arow = idx[s + min(bm0 + srow, c - 1)];
    const short* pah = Ah  + (size_t)arow * K + sk;
    const short* pal = Alp + (size_t)arow * K + sk;
    const short* pbh = Bh  + (size_t)(bn0 + srow) * K + sk;
    const short* pbl = Blp + (size_t)(bn0 + srow) * K + sk;

    f32x4 acc[4][4];
    #pragma unroll
    for (int m = 0; m < 4; m++)
        #pragma unroll
        for (int n = 0; n < 4; n++) acc[m][n] = (f32x4){0.f, 0.f, 0.f, 0.f};

    s16x8 rah[4], ral[4], rbh[4], rbl[4];
    #pragma unroll
    for (int q = 0; q < 4; q++) {
        rah[q] = *reinterpret_cast<const s16x8*>(pah + q * 8);
        ral[q] = *reinterpret_cast<const s16x8*>(pal + q * 8);
        rbh[q] = *reinterpret_cast<const s16x8*>(pbh + q * 8);
        rbl[q] = *reinterpret_cast<const s16x8*>(pbl + q * 8);
    }

    for (int k0 = 0; k0 < K; k0 += 64) {
        __syncthreads();
        #pragma unroll
        for (int q = 0; q < 4; q++) {
            *reinterpret_cast<s16x8*>(&LAh[srow * LD64 + sk + q * 8]) = rah[q];
            *reinterpret_cast<s16x8*>(&LAl[srow * LD64 + sk + q * 8]) = ral[q];
            *reinterpret_cast<s16x8*>(&LBh[srow * LD64 + sk + q * 8]) = rbh[q];
            *reinterpret_cast<s16x8*>(&LBl[srow * LD64 + sk + q * 8]) = rbl[q];
        }
        __syncthreads();
        if (k0 + 64 < K) {
            #pragma unroll
            for (int q = 0; q < 4; q++) {
                rah[q] = *reinterpret_cast<const s16x8*>(pah + k0 + 64 + q * 8);
                ral[q] = *reinterpret_cast<const s16x8*>(pal + k0 + 64 + q * 8);
                rbh[q] = *reinterpret_cast<const s16x8*>(pbh + k0 + 64 + q * 8);
                rbl[q] = *reinterpret_cast<const s16x8*>(pbl + k0 + 64 + q * 8);
            }
        }
        #pragma unroll
        for (int ks2 = 0; ks2 < 2; ks2++) {
            const int ko = ks2 * 32 + fg * 4;
            s16x8 afh[4], afl[4];
            #pragma unroll
            for (int m = 0; m < 4; m++) {
                afh[m] = ldfrag(&LAh[(wr * 64 + m * 16 + fr) * LD64 + ko]);
                afl[m] = ldfrag(&LAl[(wr * 64 + m * 16 + fr) * LD64 + ko]);
            }
            #pragma unroll
            for (int n = 0; n < 4; n++) {
                const s16x8 bh = ldfrag(&LBh[(wc * 64 + n * 16 + fr) * LD64 + ko]);
                const s16x8 bl = ldfrag(&LBl[(wc * 64 + n * 16 + fr) * LD64 + ko]);
                #pragma unroll
                for (int m = 0; m < 4; m++) {
                    acc[m][n] = __builtin_amdgcn_mfma_f32_16x16x32_bf16(afh[m], bh, acc[m][n], 0, 0, 0);
                    acc[m][n] = __builtin_amdgcn_mfma_f32_16x16x32_bf16(afl[m], bh, acc[m][n], 0, 0, 0);
                    acc[m][n] = __builtin_amdgcn_mfma_f32_16x16x32_bf16(afh[m], bl, acc[m][n], 0, 0, 0);
                }
            }
        }
    }

    #pragma unroll
    for (int m = 0; m < 4; m++)
        #pragma unroll
        for (int n = 0; n < 4; n++)
            #pragma unroll
            for (int r = 0; r < 4; r++) {
                const int row = bm0 + wr * 64 + m * 16 + fg * 4 + r;
                if (MODE >= 1 && row >= c) continue;
                const int col = bn0 + wc * 64 + n * 16 + fr;
                const size_t p = (size_t)((MODE >= 1 ? s : 0) + row) * I_ + col;
                if (!isU) {
                    Cg[p] = acc[m][n][r];
                } else {
                    const short hh = f2bf(acc[m][n][r]);
                    Cuh[p] = hh;
                    Cul[p] = f2bf(acc[m][n][r] - bf2f(hh));
                }
            }
}

extern "C" void kernel_launch(void* const* d_in, const int* in_sizes, int n_in,
                              void* d_out, int out_size, void* d_ws, size_t ws_size,
                              hipStream_t stream)
{
    const int*   ids    = (const int*)  d_in[0];
    const float* embed  = (const float*)d_in[1];
    const float* ln1_g  = (const float*)d_in[2];
    const float* ln1_b  = (const float*)d_in[3];
    const float* wq     = (const float*)d_in[4];
    const float* wk     = (const float*)d_in[5];
    const float* wv     = (const float*)d_in[6];
    const float* wo     = (const float*)d_in[7];
    const float* ln2_g  = (const float*)d_in[8];
    const float* ln2_b  = (const float*)d_in[9];
    const float* gate_w = (const float*)d_in[10];
    const float* exp_wg = (const float*)d_in[11];
    const float* exp_wu = (const float*)d_in[12];
    const float* exp_wd = (const float*)d_in[13];
    const float* sh_wg  = (const float*)d_in[14];
    const float* sh_wu  = (const float*)d_in[15];
    const float* sh_wd  = (const float*)d_in[16];
    const float* fn_g   = (const float*)d_in[17];
    const float* fn_b   = (const float*)d_in[18];
    const float* lm     = (const float*)d_in[19];
    float* out = (float*)d_out;

    float* x    = (float*)d_ws;                 // T*H
    float* h    = x + 2097152;                  // T*H
    float* qkvp = h + 2097152;                  // R1: [T][1536]; ebuf aliases
    float* ebuf = qkvp;
    float* gbuf = qkvp + 5242880;               // CAP*I f32
    float* gw   = gbuf + 5242880;               // T*8
    float* wl   = gw + (size_t)T_ * E_;         // CAP
    int*   idx  = (int*)(wl + CAP_);            // CAP
    int*   pos  = idx + CAP_;                   // T*2
    int*   cnt  = pos + 2 * T_;                 // 8
    int*   seg  = cnt + E_;                     // 8 (+pad)
    short* hhi  = (short*)(seg + 64);           // T*H
    short* hlo  = hhi + 2097152;
    short* hbf  = hlo + 2097152;
    short* obh  = hbf + 2097152;                // attn O hi
    short* obl  = obh + 2097152;                // attn O lo
    short* gbh  = obl + 2097152;                // CAP*I
    short* gbl  = gbh + 5242880;                // CAP*I
    short* wb   = gbl + 5242880;                // 56.6M shorts, phase-reused
    const size_t EW = (size_t)E_ * I_ * H_;     // 8,388,608

    short* qkvwh = wb;                          // [1536][1024] hi
    short* qkvwl = wb + 1572864;                // lo
    short* wowh  = wb + 3145728;                // [1024][1024] hi
    short* wowl  = wb + 4194304;                // lo
    short* khi_p = wb + 5242880;
    short* klo_p = khi_p + 524288;
    short* vth_p = klo_p + 524288;
    short* vtl_p = vth_p + 524288;

    k_embed<<<T_, 256, 0, stream>>>(ids, embed, x);

    for (int l = 0; l < L_; l++) {
        k_layernorm<2><<<T_, 256, 0, stream>>>(x, ln1_g + (size_t)l * H_, ln1_b + (size_t)l * H_, h, hhi, hlo);

        k_cvt_sp_t<<<dim3(16, 16), 256, 0, stream>>>(wq + (size_t)l * H_ * H_,   qkvwh,                qkvwl,                H_,  H_);
        k_cvt_sp_t<<<dim3(4, 16),  256, 0, stream>>>(wk + (size_t)l * H_ * 256,  qkvwh + 1024 * 1024,  qkvwl + 1024 * 1024,  256, H_);
        k_cvt_sp_t<<<dim3(4, 16),  256, 0, stream>>>(wv + (size_t)l * H_ * 256,  qkvwh + 1280 * 1024,  qkvwl + 1280 * 1024,  256, H_);
        k_cvt_sp_t<<<dim3(16, 16), 256, 0, stream>>>(wo + (size_t)l * H_ * H_,   wowh,                 wowl,                 H_,  H_);

        k_mfma_sp64<0, 0><<<dim3(QKVN / 128, 16, 1), 256, 0, stream>>>(
            hhi, hlo, qkvwh, qkvwl, qkvp, nullptr, nullptr, nullptr, QKVN, H_);

        k_rope_all<<<(T_ * 20 * 32) / 256, 256, 0, stream>>>(qkvp);

        k_cvt_kv<<<B_ * NKV_ * (S_ / 64), 256, 0, stream>>>(qkvp, khi_p, klo_p, vth_p, vtl_p);
        k_attn_mfma<<<dim3(S_ / 64, NH_, B_), 256, 0, stream>>>(qkvp, khi_p, klo_p, vth_p, vtl_p, obh, obl);

        k_mfma_sp64<0, 2><<<dim3(8, 16, 1), 256, 0, stream>>>(
            obh, obl, wowh, wowl, x, nullptr, nullptr, nullptr, H_, H_);

        if (l == 0)
            k_layernorm<2><<<T_, 256, 0, stream>>>(x, ln2_g + (size_t)l * H_, ln2_b + (size_t)l * H_, h, hhi, hlo);
        else
            k_layernorm<1><<<T_, 256, 0, stream>>>(x, ln2_g + (size_t)l * H_, ln2_b + (size_t)l * H_, h, hbf, nullptr);
        k_gate<<<T_, 64, 0, stream>>>(h, gate_w + (size_t)l * E_ * H_, gw);
        k_build<<<1, 512, 0, stream>>>(gw, idx, wl, pos, cnt, seg);

        const float* wg_l = exp_wg + (size_t)l * EW;
        const float* wu_l = exp_wu + (size_t)l * EW;
        const float* wd_l = exp_wd + (size_t)l * EW;
        const float* sg_l = sh_wg + (size_t)l * I_ * H_;
        const float* su_l = sh_wu + (size_t)l * I_ * H_;
        const float* sd_l = sh_wd + (size_t)l * H_ * I_;

        if (l == 0) {
            short* wgh = wb;            short* wgl = wb + EW;
            short* wuh = wb + 2 * EW;   short* wul = wb + 3 * EW;
            short* wdh = wb + 4 * EW;   short* wdl = wb + 5 * EW;
            short* sgh = wb + 6 * EW;   short* sgl = sgh + 1048576;
            short* suh = sgl + 1048576; short* sul = suh + 1048576;
            short* sdh = sul + 1048576; short* sdl = sdh + 1048576;

            k_cvt_sp<<<4096, 256, 0, stream>>>(wg_l, wgh, wgl, (int)(EW / 8));
            k_cvt_sp<<<4096, 256, 0, stream>>>(wu_l, wuh, wul, (int)(EW / 8));
            k_cvt_sp<<<4096, 256, 0, stream>>>(wd_l, wdh, wdl, (int)(EW / 8));
            k_cvt_sp<<<512,  256, 0, stream>>>(sg_l, sgh, sgl, 131072);
            k_cvt_sp<<<512,  256, 0, stream>>>(su_l, suh, sul, 131072);
            k_cvt_sp<<<512,  256, 0, stream>>>(sd_l, sdh, sdl, 131072);

            k_mfma_sp_gu64<0><<<dim3(16, 16, 1), 256, 0, stream>>>(
                hhi, hlo, sgh, sgl, suh, sul, gbuf, gbh, gbl, nullptr, nullptr, nullptr, H_);
            k_silu_sp<<<(T_ * I_) / 256, 256, 0, stream>>>(gbuf, gbh, gbl);
            k_mfma_sp64<0, 2><<<dim3(8, 16, 1), 256, 0, stream>>>(
                gbh, gbl, sdh, sdl, x, nullptr, nullptr, nullptr, H_, I_);
            k_mfma_sp_gu64<1><<<dim3(16, 16, E_), 256, 0, stream>>>(
                hhi, hlo, wgh, wgl, wuh, wul, gbuf, gbh, gbl, idx, cnt, seg, H_);
            k_silu_sp<<<(CAP_ * I_) / 256, 256, 0, stream>>>(gbuf, gbh, gbl);
            k_mfma_sp64<2, 0><<<dim3(8, 16, E_), 256, 0, stream>>>(
                gbh, gbl, wdh, wdl, ebuf, idx, cnt, seg, H_, I_);
        } else {
            short* wgb = wb;            short* wub = wb + EW;       short* wdb = wb + 2 * EW;
            short* sgb = wb + 3 * EW;   short* sub = sgb + 1048576; short* sdb = sub + 1048576;

            k_cvt<<<4096, 256, 0, stream>>>(wg_l, wgb, (int)(EW / 8));
            k_cvt<<<4096, 256, 0, stream>>>(wu_l, wub, (int)(EW / 8));
            k_cvt<<<4096, 256, 0, stream>>>(wd_l, wdb, (int)(EW / 8));
            k_cvt<<<512,  256, 0, stream>>>(sg_l, sgb, 131072);
            k_cvt<<<512,  256, 0, stream>>>(su_l, sub, 131072);
            k_cvt<<<512,  256, 0, stream>>>(sd_l, sdb, 131072);

            k_mfma_b_gu64<0><<<dim3(16, 16, 1), 256, 0, stream>>>(
                hbf, sgb, sub, gbuf, gbh, nullptr, nullptr, nullptr, H_);
            k_silu_b<<<(T_ * I_) / 256, 256, 0, stream>>>(gbuf, gbh);
            k_mfma_moe64<0, 2><<<dim3(8, 16, 1), 256, 0, stream>>>(
                gbh, sdb, x, nullptr, nullptr, nullptr, H_, I_);
            k_mfma_b_gu64<1><<<dim3(16, 16, E_), 256, 0, stream>>>(
                hbf, wgb, wub, gbuf, gbh, idx, cnt, seg, H_);
            k_silu_b<<<(CAP_ * I_) / 256, 256, 0, stream>>>(gbuf, gbh);
            k_mfma_moe64<2, 0><<<dim3(8, 16, E_), 256, 0, stream>>>(
                gbh, wdb, ebuf, idx, cnt, seg, H_, I_);
        }
        k_combine<<<(T_ * H_) / 256, 256, 0, stream>>>(x, ebuf, wl, pos);
    }

    k_layernorm<1><<<T_, 256, 0, stream>>>(x, fn_g, fn_b, h, hbf, nullptr);
    k_cvt<<<16000, 256, 0, stream>>>(lm, wb, 4096000);
    k_mfma_bt64<<<(T_ / 128) * (V_ / 128), 256, 0, stream>>>(hbf, wb, out, T_, V_, H_);
}

// Round 16
// 1466.251 us; speedup vs baseline: 1.0290x; 1.0290x over previous
//
#include <hip/hip_runtime.h>
#include <cmath>

#define L_   2
#define E_   8
#define NH_  16
#define NKV_ 4
#define HD_  64
#define H_   1024
#define I_   1024
#define B_   2
#define S_   1024
#define T_   (B_*S_)
#define V_   32000
#define CAP_ 5120
#define QKVN 1536
#define LD64  72   // LDS row stride (shorts) for BK=64 tiles
#define AST  72    // LDS row stride (shorts) for attention tiles

typedef float f32x4 __attribute__((ext_vector_type(4)));
typedef short s16x4 __attribute__((ext_vector_type(4)));
typedef short s16x8 __attribute__((ext_vector_type(8)));

__device__ __forceinline__ short f2bf(float f) {
    unsigned u = __float_as_uint(f);
    u = (u + 0x7fffu + ((u >> 16) & 1u)) >> 16;   // RNE
    return (short)u;
}
__device__ __forceinline__ float bf2f(short h) {
    return __uint_as_float(((unsigned)(unsigned short)h) << 16);
}
__device__ __forceinline__ s16x8 ldfrag(const short* p) {
    s16x4 lo = *reinterpret_cast<const s16x4*>(p);
    s16x4 hi = *reinterpret_cast<const s16x4*>(p + 16);
    return __builtin_shufflevector(lo, hi, 0, 1, 2, 3, 4, 5, 6, 7);
}

// ---------------- converters ----------------
__global__ __launch_bounds__(256)
void k_cvt(const float* __restrict__ s, short* __restrict__ d, int n8)
{
    const int i = blockIdx.x * 256 + threadIdx.x;
    if (i >= n8) return;
    const float4 a = *reinterpret_cast<const float4*>(s + (size_t)i * 8);
    const float4 b = *reinterpret_cast<const float4*>(s + (size_t)i * 8 + 4);
    s16x8 o;
    o[0]=f2bf(a.x); o[1]=f2bf(a.y); o[2]=f2bf(a.z); o[3]=f2bf(a.w);
    o[4]=f2bf(b.x); o[5]=f2bf(b.y); o[6]=f2bf(b.z); o[7]=f2bf(b.w);
    *reinterpret_cast<s16x8*>(d + (size_t)i * 8) = o;
}

__global__ __launch_bounds__(256)
void k_cvt_sp(const float* __restrict__ s, short* __restrict__ dh, short* __restrict__ dl, int n8)
{
    const int i = blockIdx.x * 256 + threadIdx.x;
    if (i >= n8) return;
    const float4 a = *reinterpret_cast<const float4*>(s + (size_t)i * 8);
    const float4 b = *reinterpret_cast<const float4*>(s + (size_t)i * 8 + 4);
    float v[8] = {a.x, a.y, a.z, a.w, b.x, b.y, b.z, b.w};
    s16x8 oh, ol;
    #pragma unroll
    for (int j = 0; j < 8; j++) {
        const short hh = f2bf(v[j]);
        oh[j] = hh;
        ol[j] = f2bf(v[j] - bf2f(hh));
    }
    *reinterpret_cast<s16x8*>(dh + (size_t)i * 8) = oh;
    *reinterpret_cast<s16x8*>(dl + (size_t)i * 8) = ol;
}

// ---------------- transposing split converter ----------------
__global__ __launch_bounds__(256)
void k_cvt_sp_t(const float* __restrict__ w, short* __restrict__ oh, short* __restrict__ ol,
                int N, int K)
{
    const int n0 = blockIdx.x * 64, k0 = blockIdx.y * 64;
    const int r = threadIdx.x >> 2, c0 = (threadIdx.x & 3) * 16;
    __shared__ float Tt[64][65];
    const float* src = w + (size_t)(k0 + r) * N + n0 + c0;
    #pragma unroll
    for (int g = 0; g < 4; g++) {
        const float4 a = *reinterpret_cast<const float4*>(src + g * 4);
        Tt[c0 + g*4 + 0][r] = a.x; Tt[c0 + g*4 + 1][r] = a.y;
        Tt[c0 + g*4 + 2][r] = a.z; Tt[c0 + g*4 + 3][r] = a.w;
    }
    __syncthreads();
    const size_t o = (size_t)(n0 + r) * K + k0 + c0;
    #pragma unroll
    for (int g = 0; g < 2; g++) {
        s16x8 vh, vl;
        #pragma unroll
        for (int j = 0; j < 8; j++) {
            const float v = Tt[r][c0 + g * 8 + j];
            const short hh = f2bf(v);
            vh[j] = hh; vl[j] = f2bf(v - bf2f(hh));
        }
        *reinterpret_cast<s16x8*>(oh + o + g * 8) = vh;
        *reinterpret_cast<s16x8*>(ol + o + g * 8) = vl;
    }
}

// ---------------- K/V -> split bf16 ----------------
__global__ __launch_bounds__(256)
void k_cvt_kv(const float* __restrict__ qkvp,
              short* __restrict__ khi, short* __restrict__ klo,
              short* __restrict__ vth, short* __restrict__ vtl)
{
    const int blk = blockIdx.x;
    const int s0  = (blk & 15) * 64;
    const int kvh = (blk >> 4) & 3;
    const int b   = blk >> 6;
    const int tid = threadIdx.x;
    const int r = tid >> 2, c0 = (tid & 3) * 16;
    __shared__ float Vt[64][65];

    const float* kp = qkvp + (size_t)(b * S_ + s0 + r) * QKVN + 1024 + kvh * 64 + c0;
    const size_t ko = ((size_t)(b * 4 + kvh) * S_ + s0 + r) * 64 + c0;
    #pragma unroll
    for (int g = 0; g < 2; g++) {
        const float4 a = *reinterpret_cast<const float4*>(kp + g * 8);
        const float4 bq = *reinterpret_cast<const float4*>(kp + g * 8 + 4);
        float v[8] = {a.x, a.y, a.z, a.w, bq.x, bq.y, bq.z, bq.w};
        s16x8 oh, ol;
        #pragma unroll
        for (int j = 0; j < 8; j++) {
            const short hh = f2bf(v[j]);
            oh[j] = hh; ol[j] = f2bf(v[j] - bf2f(hh));
        }
        *reinterpret_cast<s16x8*>(khi + ko + g * 8) = oh;
        *reinterpret_cast<s16x8*>(klo + ko + g * 8) = ol;
    }
    const float* vp = kp + 256;
    #pragma unroll
    for (int g = 0; g < 4; g++) {
        const float4 a = *reinterpret_cast<const float4*>(vp + g * 4);
        Vt[c0 + g*4 + 0][r] = a.x; Vt[c0 + g*4 + 1][r] = a.y;
        Vt[c0 + g*4 + 2][r] = a.z; Vt[c0 + g*4 + 3][r] = a.w;
    }
    __syncthreads();
    const size_t vo = ((size_t)(b * 4 + kvh) * 64 + r) * S_ + s0 + c0;
    #pragma unroll
    for (int g = 0; g < 2; g++) {
        s16x8 oh, ol;
        #pragma unroll
        for (int j = 0; j < 8; j++) {
            const float v = Vt[r][c0 + g * 8 + j];
            const short hh = f2bf(v);
            oh[j] = hh; ol[j] = f2bf(v - bf2f(hh));
        }
        *reinterpret_cast<s16x8*>(vth + vo + g * 8) = oh;
        *reinterpret_cast<s16x8*>(vtl + vo + g * 8) = ol;
    }
}

// ---------------- embedding ----------------
__global__ void k_embed(const int* __restrict__ ids, const float* __restrict__ emb,
                        float* __restrict__ x)
{
    const int t = blockIdx.x;
    const float* src = emb + (size_t)ids[t] * H_;
    float* dst = x + (size_t)t * H_;
    for (int i = threadIdx.x; i < H_; i += 256) dst[i] = src[i];
}

// ---------------- layernorm (OMODE 0: f32 | 1: +bf16 | 2: +hi/lo split) ----------------
template<int OMODE>
__global__ __launch_bounds__(256)
void k_layernorm(const float* __restrict__ x, const float* __restrict__ g,
                 const float* __restrict__ bb, float* __restrict__ out,
                 short* __restrict__ oh, short* __restrict__ ol)
{
    const int t = blockIdx.x;
    const float* row = x + (size_t)t * H_;
    float s = 0.f, ss = 0.f;
    for (int i = threadIdx.x; i < H_; i += 256) { const float v = row[i]; s += v; ss += v * v; }
    #pragma unroll
    for (int off = 32; off > 0; off >>= 1) {
        s  += __shfl_down(s, off, 64);
        ss += __shfl_down(ss, off, 64);
    }
    __shared__ float shs[4], shss[4];
    const int w = threadIdx.x >> 6;
    if ((threadIdx.x & 63) == 0) { shs[w] = s; shss[w] = ss; }
    __syncthreads();
    const float fs  = shs[0] + shs[1] + shs[2] + shs[3];
    const float fss = shss[0] + shss[1] + shss[2] + shss[3];
    const float mean = fs * (1.f / H_);
    const float var  = fss * (1.f / H_) - mean * mean;
    const float rstd = 1.0f / sqrtf(var + 1e-5f);
    float* orow = out + (size_t)t * H_;
    for (int i = threadIdx.x; i < H_; i += 256) {
        const float v = (row[i] - mean) * rstd * g[i] + bb[i];
        orow[i] = v;
        if (OMODE == 1) {
            oh[(size_t)t * H_ + i] = f2bf(v);
        } else if (OMODE == 2) {
            const short hh = f2bf(v);
            oh[(size_t)t * H_ + i] = hh;
            ol[(size_t)t * H_ + i] = f2bf(v - bf2f(hh));
        }
    }
}

// ---------------- fused RoPE: q (16 heads) + k (4 heads) ----------------
__global__ void k_rope_all(float* __restrict__ x)
{
    const int idx  = blockIdx.x * 256 + threadIdx.x;
    const int i    = idx & 31;
    const int rest = idx >> 5;
    const int head = rest % 20;
    const int t    = rest / 20;
    const int pos  = t & (S_ - 1);
    const float p32  = (float)pow(1.0e6, (double)i / 32.0);
    const float invf = 1.0f / p32;
    const float ang  = (float)pos * invf;
    const float c = (float)cos((double)ang);
    const float s = (float)sin((double)ang);
    const int off = (head < 16) ? head * 64 : 1024 + (head - 16) * 64;
    float* base = x + (size_t)t * QKVN + off;
    const float x1 = base[i];
    const float x2 = base[i + 32];
    base[i]      = x1 * c - x2 * s;
    base[i + 32] = x2 * c + x1 * s;
}

// ---------------- split-bf16 MFMA flash attention ----------------
__global__ __launch_bounds__(256)
void k_attn_mfma(const float* __restrict__ q,
                 const short* __restrict__ khi, const short* __restrict__ klo,
                 const short* __restrict__ vth, const short* __restrict__ vtl,
                 short* __restrict__ obh, short* __restrict__ obl)
{
    const int q0 = blockIdx.x * 64, h = blockIdx.y, b = blockIdx.z;
    const int kvh = h >> 2;
    const int tid = threadIdx.x, lane = tid & 63, w = tid >> 6;
    const int fr = lane & 15, fg = lane >> 4;

    __shared__ short Qh[64 * AST], Ql[64 * AST];
    __shared__ short Kh[64 * AST], Kl[64 * AST];
    __shared__ short Vh[64 * AST], Vl[64 * AST];
    __shared__ short Ph[64 * AST], Pl[64 * AST];

    {
        const int r = tid >> 2, c0 = (tid & 3) * 16;
        const float* qs = q + (size_t)(b * S_ + q0 + r) * QKVN + h * HD_ + c0;
        #pragma unroll
        for (int g = 0; g < 2; g++) {
            const float4 a = *reinterpret_cast<const float4*>(qs + g * 8);
            const float4 bq = *reinterpret_cast<const float4*>(qs + g * 8 + 4);
            float v[8] = {a.x, a.y, a.z, a.w, bq.x, bq.y, bq.z, bq.w};
            s16x8 oh, ol;
            #pragma unroll
            for (int j = 0; j < 8; j++) {
                const float sv = v[j] * 0.125f;
                const short hh = f2bf(sv);
                oh[j] = hh; ol[j] = f2bf(sv - bf2f(hh));
            }
            *reinterpret_cast<s16x8*>(&Qh[r * AST + c0 + g * 8]) = oh;
            *reinterpret_cast<s16x8*>(&Ql[r * AST + c0 + g * 8]) = ol;
        }
    }

    f32x4 accO[4];
    #pragma unroll
    for (int n = 0; n < 4; n++) accO[n] = (f32x4){0.f, 0.f, 0.f, 0.f};
    float rs[4] = {0.f, 0.f, 0.f, 0.f};

    const size_t kbase = (size_t)(b * 4 + kvh) * S_ * 64;
    const size_t vbase = (size_t)(b * 4 + kvh) * 64 * S_;
    const int nkb = (q0 >> 6) + 1;

    for (int kb = 0; kb < nkb; kb++) {
        const int j0 = kb * 64;
        __syncthreads();
        {
            const int r = tid >> 2, c0 = (tid & 3) * 16;
            const short* ks = khi + kbase + (size_t)(j0 + r) * 64 + c0;
            const short* ls = klo + kbase + (size_t)(j0 + r) * 64 + c0;
            *reinterpret_cast<s16x8*>(&Kh[r * AST + c0])     = *reinterpret_cast<const s16x8*>(ks);
            *reinterpret_cast<s16x8*>(&Kh[r * AST + c0 + 8]) = *reinterpret_cast<const s16x8*>(ks + 8);
            *reinterpret_cast<s16x8*>(&Kl[r * AST + c0])     = *reinterpret_cast<const s16x8*>(ls);
            *reinterpret_cast<s16x8*>(&Kl[r * AST + c0 + 8]) = *reinterpret_cast<const s16x8*>(ls + 8);
            const short* vs = vth + vbase + (size_t)r * S_ + j0 + c0;
            const short* vl = vtl + vbase + (size_t)r * S_ + j0 + c0;
            *reinterpret_cast<s16x8*>(&Vh[r * AST + c0])     = *reinterpret_cast<const s16x8*>(vs);
            *reinterpret_cast<s16x8*>(&Vh[r * AST + c0 + 8]) = *reinterpret_cast<const s16x8*>(vs + 8);
            *reinterpret_cast<s16x8*>(&Vl[r * AST + c0])     = *reinterpret_cast<const s16x8*>(vl);
            *reinterpret_cast<s16x8*>(&Vl[r * AST + c0 + 8]) = *reinterpret_cast<const s16x8*>(vl + 8);
        }
        __syncthreads();

        f32x4 accS[4];
        #pragma unroll
        for (int n = 0; n < 4; n++) accS[n] = (f32x4){0.f, 0.f, 0.f, 0.f};
        #pragma unroll
        for (int ks2 = 0; ks2 < 2; ks2++) {
            const int ko = ks2 * 32 + fg * 4;
            const s16x8 ah = ldfrag(&Qh[(w * 16 + fr) * AST + ko]);
            const s16x8 al = ldfrag(&Ql[(w * 16 + fr) * AST + ko]);
            #pragma unroll
            for (int n = 0; n < 4; n++) {
                const int base = (n * 16 + fr) * AST + ko;
                const s16x8 bh = ldfrag(&Kh[base]);
                const s16x8 bl = ldfrag(&Kl[base]);
                accS[n] = __builtin_amdgcn_mfma_f32_16x16x32_bf16(ah, bh, accS[n], 0, 0, 0);
                accS[n] = __builtin_amdgcn_mfma_f32_16x16x32_bf16(al, bh, accS[n], 0, 0, 0);
                accS[n] = __builtin_amdgcn_mfma_f32_16x16x32_bf16(ah, bl, accS[n], 0, 0, 0);
            }
        }

        #pragma unroll
        for (int r = 0; r < 4; r++) {
            const int qrow = q0 + w * 16 + fg * 4 + r;
            float ev[4];
            float p = 0.f;
            #pragma unroll
            for (int n = 0; n < 4; n++) {
                const int key = j0 + n * 16 + fr;
                const float e = (key <= qrow) ? expf(accS[n][r]) : 0.f;
                ev[n] = e; p += e;
            }
            p += __shfl_xor(p, 1, 64); p += __shfl_xor(p, 2, 64);
            p += __shfl_xor(p, 4, 64); p += __shfl_xor(p, 8, 64);
            rs[r] += p;
            #pragma unroll
            for (int n = 0; n < 4; n++) {
                const int addr = (w * 16 + fg * 4 + r) * AST + n * 16 + fr;
                const short hh = f2bf(ev[n]);
                Ph[addr] = hh;
                Pl[addr] = f2bf(ev[n] - bf2f(hh));
            }
        }
        __builtin_amdgcn_wave_barrier();

        #pragma unroll
        for (int ks2 = 0; ks2 < 2; ks2++) {
            const int ko = ks2 * 32 + fg * 4;
            const s16x8 ph = ldfrag(&Ph[(w * 16 + fr) * AST + ko]);
            const s16x8 pl = ldfrag(&Pl[(w * 16 + fr) * AST + ko]);
            #pragma unroll
            for (int n = 0; n < 4; n++) {
                const int base = (n * 16 + fr) * AST + ko;
                const s16x8 vh = ldfrag(&Vh[base]);
                const s16x8 vl = ldfrag(&Vl[base]);
                accO[n] = __builtin_amdgcn_mfma_f32_16x16x32_bf16(ph, vh, accO[n], 0, 0, 0);
                accO[n] = __builtin_amdgcn_mfma_f32_16x16x32_bf16(pl, vh, accO[n], 0, 0, 0);
                accO[n] = __builtin_amdgcn_mfma_f32_16x16x32_bf16(ph, vl, accO[n], 0, 0, 0);
            }
        }
    }

    #pragma unroll
    for (int r = 0; r < 4; r++) {
        const float inv = 1.0f / rs[r];
        const int qrow = q0 + w * 16 + fg * 4 + r;
        const size_t ob = (size_t)(b * S_ + qrow) * H_ + h * HD_;
        #pragma unroll
        for (int n = 0; n < 4; n++) {
            const float v = accO[n][r] * inv;
            const short hh = f2bf(v);
            obh[ob + n * 16 + fr] = hh;
            obl[ob + n * 16 + fr] = f2bf(v - bf2f(hh));
        }
    }
}

// ---------------- MoE gate ----------------
__global__ __launch_bounds__(64)
void k_gate(const float* __restrict__ h, const float* __restrict__ gwt, float* __restrict__ w)
{
    const int t = blockIdx.x;
    const int lane = threadIdx.x;
    const float* row = h + (size_t)t * H_;
    float acc[E_];
    #pragma unroll
    for (int e = 0; e < E_; e++) acc[e] = 0.f;
    for (int i = lane; i < H_; i += 64) {
        const float xv = row[i];
        #pragma unroll
        for (int e = 0; e < E_; e++) acc[e] += xv * gwt[(size_t)e * H_ + i];
    }
    #pragma unroll
    for (int e = 0; e < E_; e++) {
        #pragma unroll
        for (int off = 32; off > 0; off >>= 1) acc[e] += __shfl_down(acc[e], off, 64);
    }
    if (lane == 0) {
        int i1 = 0; float m1 = acc[0];
        #pragma unroll
        for (int e = 1; e < E_; e++) if (acc[e] > m1) { m1 = acc[e]; i1 = e; }
        int i2 = -1; float m2 = -1e30f;
        #pragma unroll
        for (int e = 0; e < E_; e++) if (e != i1 && acc[e] > m2) { m2 = acc[e]; i2 = e; }
        const float e2  = expf(m2 - m1);
        const float den = 1.0f + e2;
        #pragma unroll
        for (int e = 0; e < E_; e++)
            w[t * E_ + e] = (e == i1) ? (1.0f / den) : ((e == i2) ? (e2 / den) : 0.f);
    }
}

// ---------------- build per-expert token lists ----------------
__global__ __launch_bounds__(512)
void k_build(const float* __restrict__ gw, int* __restrict__ idx, float* __restrict__ wl,
             int* __restrict__ pos, int* __restrict__ cnt, int* __restrict__ seg)
{
    const int e = threadIdx.x >> 6;
    const int lane = threadIdx.x & 63;
    __shared__ int scnt[E_], sseg[E_];
    int c = 0;
    for (int t0 = 0; t0 < T_; t0 += 64) {
        const float v = gw[(size_t)(t0 + lane) * E_ + e];
        c += __popcll(__ballot(v > 0.f));
    }
    if (lane == 0) scnt[e] = c;
    __syncthreads();
    if (threadIdx.x == 0) {
        int off = 0;
        for (int q = 0; q < E_; q++) {
            sseg[q] = off; cnt[q] = scnt[q]; seg[q] = off;
            off += (scnt[q] + 127) & ~127;
        }
    }
    __syncthreads();
    int p = sseg[e];
    for (int t0 = 0; t0 < T_; t0 += 64) {
        const int t = t0 + lane;
        const float v = gw[(size_t)t * E_ + e];
        const unsigned long long m = __ballot(v > 0.f);
        if (v > 0.f) {
            const int pp = p + __popcll(m & ((1ull << lane) - 1ull));
            idx[pp] = t; wl[pp] = v;
            int slot = 0;
            for (int q = 0; q < e; q++) slot += (gw[(size_t)t * E_ + q] > 0.f) ? 1 : 0;
            pos[t * 2 + slot] = pp;
        }
        p += __popcll(m);
    }
}

// ---------------- combine ----------------
__global__ void k_combine(float* __restrict__ x, const float* __restrict__ ebuf,
                          const float* __restrict__ wl, const int* __restrict__ pos)
{
    const int id = blockIdx.x * 256 + threadIdx.x;
    const int t = id >> 10;
    const int hc = id & 1023;
    const int p0 = pos[t * 2], p1 = pos[t * 2 + 1];
    x[id] += wl[p0] * ebuf[(size_t)p0 * H_ + hc] + wl[p1] * ebuf[(size_t)p1 * H_ + hc];
}

// ---------------- silu combines ----------------
__global__ __launch_bounds__(256)
void k_silu_sp(const float* __restrict__ g, short* __restrict__ uh, short* __restrict__ ul)
{
    const size_t i = (size_t)blockIdx.x * 256 + threadIdx.x;
    const float gv = g[i];
    const float u = bf2f(uh[i]) + bf2f(ul[i]);
    const float p = gv * (1.f / (1.f + expf(-gv))) * u;
    const short hh = f2bf(p);
    uh[i] = hh;
    ul[i] = f2bf(p - bf2f(hh));
}

__global__ __launch_bounds__(256)
void k_silu_b(const float* __restrict__ g, short* __restrict__ ub)
{
    const size_t i = (size_t)blockIdx.x * 256 + threadIdx.x;
    const float gv = g[i];
    const float p = gv * (1.f / (1.f + expf(-gv))) * bf2f(ub[i]);
    ub[i] = f2bf(p);
}

// ---------------- bf16-input MFMA GEMM, BK=64 (lm_head), XCD-swizzled ----------------
__global__ __launch_bounds__(256)
void k_mfma_bt64(const short* __restrict__ A, const short* __restrict__ Bm,
                 float* __restrict__ C, int M, int N, int K)
{
    __shared__ short Als[128 * LD64];
    __shared__ short Bls[128 * LD64];
    const int mB = M >> 7;
    const int nwg = mB * (N >> 7);
    int l = blockIdx.x;
    l = (l & 7) * (nwg >> 3) + (l >> 3);     // bijective XCD swizzle (nwg % 8 == 0)
    const int g  = l / (mB * 8);
    const int ii = l - g * (mB * 8);
    const int bm0 = (ii % mB) * 128;
    const int bn0 = (g * 8 + ii / mB) * 128;

    const int tid  = threadIdx.x;
    const int lane = tid & 63, w = tid >> 6;
    const int wr = w >> 1, wc = w & 1;
    const int fr = lane & 15, fg = lane >> 4;
    const int srow = tid >> 1, sk = (tid & 1) * 32;

    const short* pa = A  + (size_t)(bm0 + srow) * K + sk;
    const short* pb = Bm + (size_t)(bn0 + srow) * K + sk;

    f32x4 acc[4][4];
    #pragma unroll
    for (int m = 0; m < 4; m++)
        #pragma unroll
        for (int n = 0; n < 4; n++) acc[m][n] = (f32x4){0.f, 0.f, 0.f, 0.f};

    s16x8 ra[4], rb[4];
    #pragma unroll
    for (int q = 0; q < 4; q++) {
        ra[q] = *reinterpret_cast<const s16x8*>(pa + q * 8);
        rb[q] = *reinterpret_cast<const s16x8*>(pb + q * 8);
    }

    for (int k0 = 0; k0 < K; k0 += 64) {
        __syncthreads();
        #pragma unroll
        for (int q = 0; q < 4; q++) {
            *reinterpret_cast<s16x8*>(&Als[srow * LD64 + sk + q * 8]) = ra[q];
            *reinterpret_cast<s16x8*>(&Bls[srow * LD64 + sk + q * 8]) = rb[q];
        }
        __syncthreads();
        if (k0 + 64 < K) {
            #pragma unroll
            for (int q = 0; q < 4; q++) {
                ra[q] = *reinterpret_cast<const s16x8*>(pa + k0 + 64 + q * 8);
                rb[q] = *reinterpret_cast<const s16x8*>(pb + k0 + 64 + q * 8);
            }
        }
        #pragma unroll
        for (int ks2 = 0; ks2 < 2; ks2++) {
            const int ko = ks2 * 32 + fg * 4;
            s16x8 af[4], bfv[4];
            #pragma unroll
            for (int m = 0; m < 4; m++)
                af[m] = ldfrag(&Als[(wr * 64 + m * 16 + fr) * LD64 + ko]);
            #pragma unroll
            for (int n = 0; n < 4; n++)
                bfv[n] = ldfrag(&Bls[(wc * 64 + n * 16 + fr) * LD64 + ko]);
            #pragma unroll
            for (int m = 0; m < 4; m++)
                #pragma unroll
                for (int n = 0; n < 4; n++)
                    acc[m][n] = __builtin_amdgcn_mfma_f32_16x16x32_bf16(af[m], bfv[n], acc[m][n], 0, 0, 0);
        }
    }

    #pragma unroll
    for (int m = 0; m < 4; m++)
        #pragma unroll
        for (int n = 0; n < 4; n++)
            #pragma unroll
            for (int r = 0; r < 4; r++) {
                const int row = bm0 + wr * 64 + m * 16 + fg * 4 + r;
                const int col = bn0 + wc * 64 + n * 16 + fr;
                C[(size_t)row * N + col] = acc[m][n][r];
            }
}

// ---------------- bf16-input MFMA MoE GEMM, BK=64 (L2; sd/wd) ----------------
template<int MODE, int EPI>
__global__ __launch_bounds__(256)
void k_mfma_moe64(const short* __restrict__ A, const short* __restrict__ Bm,
                  float* __restrict__ Cf,
                  const int* __restrict__ idx, const int* __restrict__ cnt,
                  const int* __restrict__ seg, int N, int K)
{
    int c = T_, s = 0;
    const int bm0 = blockIdx.y * 128, bn0 = blockIdx.x * 128;
    if (MODE >= 1) {
        const int e = blockIdx.z;
        c = cnt[e];
        if (bm0 >= c) return;
        s = seg[e];
        Bm += (size_t)e * N * K;
    }
    __shared__ short Als[128 * LD64];
    __shared__ short Bls[128 * LD64];
    const int tid  = threadIdx.x;
    const int lane = tid & 63, w = tid >> 6;
    const int wr = w >> 1, wc = w & 1;
    const int fr = lane & 15, fg = lane >> 4;
    const int srow = tid >> 1, sk = (tid & 1) * 32;

    int arow;
    if (MODE == 0)      arow = bm0 + srow;
    else if (MODE == 1) arow = idx[s + min(bm0 + srow, c - 1)];
    else                arow = s + min(bm0 + srow, c - 1);
    const short* pa = A  + (size_t)arow * K + sk;
    const short* pb = Bm + (size_t)(bn0 + srow) * K + sk;

    f32x4 acc[4][4];
    #pragma unroll
    for (int m = 0; m < 4; m++)
        #pragma unroll
        for (int n = 0; n < 4; n++) acc[m][n] = (f32x4){0.f, 0.f, 0.f, 0.f};

    s16x8 ra[4], rb[4];
    #pragma unroll
    for (int q = 0; q < 4; q++) {
        ra[q] = *reinterpret_cast<const s16x8*>(pa + q * 8);
        rb[q] = *reinterpret_cast<const s16x8*>(pb + q * 8);
    }

    for (int k0 = 0; k0 < K; k0 += 64) {
        __syncthreads();
        #pragma unroll
        for (int q = 0; q < 4; q++) {
            *reinterpret_cast<s16x8*>(&Als[srow * LD64 + sk + q * 8]) = ra[q];
            *reinterpret_cast<s16x8*>(&Bls[srow * LD64 + sk + q * 8]) = rb[q];
        }
        __syncthreads();
        if (k0 + 64 < K) {
            #pragma unroll
            for (int q = 0; q < 4; q++) {
                ra[q] = *reinterpret_cast<const s16x8*>(pa + k0 + 64 + q * 8);
                rb[q] = *reinterpret_cast<const s16x8*>(pb + k0 + 64 + q * 8);
            }
        }
        #pragma unroll
        for (int ks2 = 0; ks2 < 2; ks2++) {
            const int ko = ks2 * 32 + fg * 4;
            s16x8 af[4], bfv[4];
            #pragma unroll
            for (int m = 0; m < 4; m++)
                af[m] = ldfrag(&Als[(wr * 64 + m * 16 + fr) * LD64 + ko]);
            #pragma unroll
            for (int n = 0; n < 4; n++)
                bfv[n] = ldfrag(&Bls[(wc * 64 + n * 16 + fr) * LD64 + ko]);
            #pragma unroll
            for (int m = 0; m < 4; m++)
                #pragma unroll
                for (int n = 0; n < 4; n++)
                    acc[m][n] = __builtin_amdgcn_mfma_f32_16x16x32_bf16(af[m], bfv[n], acc[m][n], 0, 0, 0);
        }
    }

    #pragma unroll
    for (int m = 0; m < 4; m++)
        #pragma unroll
        for (int n = 0; n < 4; n++)
            #pragma unroll
            for (int r = 0; r < 4; r++) {
                const int row = bm0 + wr * 64 + m * 16 + fg * 4 + r;
                if (MODE >= 1 && row >= c) continue;
                const int col = bn0 + wc * 64 + n * 16 + fr;
                const size_t p = (size_t)((MODE >= 1 ? s : 0) + row) * N + col;
                if (EPI == 0) Cf[p] = acc[m][n][r];
                else          Cf[p] += acc[m][n][r];
            }
}

// ---------------- plain bf16 fused wg|wu GEMM, BK=64 (L2) ----------------
template<int MODE>
__global__ __launch_bounds__(256)
void k_mfma_b_gu64(const short* __restrict__ A, const short* __restrict__ Bg,
                   const short* __restrict__ Bu, float* __restrict__ Cg,
                   short* __restrict__ Cu,
                   const int* __restrict__ idx, const int* __restrict__ cnt,
                   const int* __restrict__ seg, int K)
{
    int c = T_, s = 0;
    const int bm0 = blockIdx.y * 128;
    const int bn0all = blockIdx.x * 128;
    if (MODE >= 1) {
        const int e = blockIdx.z;
        c = cnt[e];
        if (bm0 >= c) return;
        s = seg[e];
        Bg += (size_t)e * I_ * K;
        Bu += (size_t)e * I_ * K;
    }
    const int isU = (bn0all >= I_) ? 1 : 0;
    const int bn0 = bn0all - isU * I_;
    const short* Bm = isU ? Bu : Bg;

    __shared__ short Als[128 * LD64];
    __shared__ short Bls[128 * LD64];
    const int tid  = threadIdx.x;
    const int lane = tid & 63, w = tid >> 6;
    const int wr = w >> 1, wc = w & 1;
    const int fr = lane & 15, fg = lane >> 4;
    const int srow = tid >> 1, sk = (tid & 1) * 32;

    int arow;
    if (MODE == 0) arow = bm0 + srow;
    else           arow = idx[s + min(bm0 + srow, c - 1)];
    const short* pa = A  + (size_t)arow * K + sk;
    const short* pb = Bm + (size_t)(bn0 + srow) * K + sk;

    f32x4 acc[4][4];
    #pragma unroll
    for (int m = 0; m < 4; m++)
        #pragma unroll
        for (int n = 0; n < 4; n++) acc[m][n] = (f32x4){0.f, 0.f, 0.f, 0.f};

    s16x8 ra[4], rb[4];
    #pragma unroll
    for (int q = 0; q < 4; q++) {
        ra[q] = *reinterpret_cast<const s16x8*>(pa + q * 8);
        rb[q] = *reinterpret_cast<const s16x8*>(pb + q * 8);
    }

    for (int k0 = 0; k0 < K; k0 += 64) {
        __syncthreads();
        #pragma unroll
        for (int q = 0; q < 4; q++) {
            *reinterpret_cast<s16x8*>(&Als[srow * LD64 + sk + q * 8]) = ra[q];
            *reinterpret_cast<s16x8*>(&Bls[srow * LD64 + sk + q * 8]) = rb[q];
        }
        __syncthreads();
        if (k0 + 64 < K) {
            #pragma unroll
            for (int q = 0; q < 4; q++) {
                ra[q] = *reinterpret_cast<const s16x8*>(pa + k0 + 64 + q * 8);
                rb[q] = *reinterpret_cast<const s16x8*>(pb + k0 + 64 + q * 8);
            }
        }
        #pragma unroll
        for (int ks2 = 0; ks2 < 2; ks2++) {
            const int ko = ks2 * 32 + fg * 4;
            s16x8 af[4], bfv[4];
            #pragma unroll
            for (int m = 0; m < 4; m++)
                af[m] = ldfrag(&Als[(wr * 64 + m * 16 + fr) * LD64 + ko]);
            #pragma unroll
            for (int n = 0; n < 4; n++)
                bfv[n] = ldfrag(&Bls[(wc * 64 + n * 16 + fr) * LD64 + ko]);
            #pragma unroll
            for (int m = 0; m < 4; m++)
                #pragma unroll
                for (int n = 0; n < 4; n++)
                    acc[m][n] = __builtin_amdgcn_mfma_f32_16x16x32_bf16(af[m], bfv[n], acc[m][n], 0, 0, 0);
        }
    }

    #pragma unroll
    for (int m = 0; m < 4; m++)
        #pragma unroll
        for (int n = 0; n < 4; n++)
            #pragma unroll
            for (int r = 0; r < 4; r++) {
                const int row = bm0 + wr * 64 + m * 16 + fg * 4 + r;
                if (MODE >= 1 && row >= c) continue;
                const int col = bn0 + wc * 64 + n * 16 + fr;
                const size_t p = (size_t)((MODE >= 1 ? s : 0) + row) * I_ + col;
                if (!isU) Cg[p] = acc[m][n][r];
                else      Cu[p] = f2bf(acc[m][n][r]);
            }
}

// ---------------- split-bf16 MFMA GEMM, BK=64 (routing-safe; qkv/wo/sd/wd) ----------------
// EPI 0: store f32 | 2: += f32
template<int MODE, int EPI>
__global__ __launch_bounds__(256)
void k_mfma_sp64(const short* __restrict__ Ah, const short* __restrict__ Alp,
                 const short* __restrict__ Bh, const short* __restrict__ Blp,
                 float* __restrict__ Cf,
                 const int* __restrict__ idx, const int* __restrict__ cnt,
                 const int* __restrict__ seg, int N, int K)
{
    int c = T_, s = 0;
    const int bm0 = blockIdx.y * 128, bn0 = blockIdx.x * 128;
    if (MODE >= 1) {
        const int e = blockIdx.z;
        c = cnt[e];
        if (bm0 >= c) return;
        s = seg[e];
        Bh  += (size_t)e * N * K;
        Blp += (size_t)e * N * K;
    }
    __shared__ short LAh[128 * LD64];
    __shared__ short LAl[128 * LD64];
    __shared__ short LBh[128 * LD64];
    __shared__ short LBl[128 * LD64];
    const int tid  = threadIdx.x;
    const int lane = tid & 63, w = tid >> 6;
    const int wr = w >> 1, wc = w & 1;
    const int fr = lane & 15, fg = lane >> 4;
    const int srow = tid >> 1, sk = (tid & 1) * 32;

    int arow;
    if (MODE == 0)      arow = bm0 + srow;
    else if (MODE == 1) arow = idx[s + min(bm0 + srow, c - 1)];
    else                arow = s + min(bm0 + srow, c - 1);
    const short* pah = Ah  + (size_t)arow * K + sk;
    const short* pal = Alp + (size_t)arow * K + sk;
    const short* pbh = Bh  + (size_t)(bn0 + srow) * K + sk;
    const short* pbl = Blp + (size_t)(bn0 + srow) * K + sk;

    f32x4 acc[4][4];
    #pragma unroll
    for (int m = 0; m < 4; m++)
        #pragma unroll
        for (int n = 0; n < 4; n++) acc[m][n] = (f32x4){0.f, 0.f, 0.f, 0.f};

    s16x8 rah[4], ral[4], rbh[4], rbl[4];
    #pragma unroll
    for (int q = 0; q < 4; q++) {
        rah[q] = *reinterpret_cast<const s16x8*>(pah + q * 8);
        ral[q] = *reinterpret_cast<const s16x8*>(pal + q * 8);
        rbh[q] = *reinterpret_cast<const s16x8*>(pbh + q * 8);
        rbl[q] = *reinterpret_cast<const s16x8*>(pbl + q * 8);
    }

    for (int k0 = 0; k0 < K; k0 += 64) {
        __syncthreads();
        #pragma unroll
        for (int q = 0; q < 4; q++) {
            *reinterpret_cast<s16x8*>(&LAh[srow * LD64 + sk + q * 8]) = rah[q];
            *reinterpret_cast<s16x8*>(&LAl[srow * LD64 + sk + q * 8]) = ral[q];
            *reinterpret_cast<s16x8*>(&LBh[srow * LD64 + sk + q * 8]) = rbh[q];
            *reinterpret_cast<s16x8*>(&LBl[srow * LD64 + sk + q * 8]) = rbl[q];
        }
        __syncthreads();
        if (k0 + 64 < K) {
            #pragma unroll
            for (int q = 0; q < 4; q++) {
                rah[q] = *reinterpret_cast<const s16x8*>(pah + k0 + 64 + q * 8);
                ral[q] = *reinterpret_cast<const s16x8*>(pal + k0 + 64 + q * 8);
                rbh[q] = *reinterpret_cast<const s16x8*>(pbh + k0 + 64 + q * 8);
                rbl[q] = *reinterpret_cast<const s16x8*>(pbl + k0 + 64 + q * 8);
            }
        }
        #pragma unroll
        for (int ks2 = 0; ks2 < 2; ks2++) {
            const int ko = ks2 * 32 + fg * 4;
            s16x8 afh[4], afl[4];
            #pragma unroll
            for (int m = 0; m < 4; m++) {
                afh[m] = ldfrag(&LAh[(wr * 64 + m * 16 + fr) * LD64 + ko]);
                afl[m] = ldfrag(&LAl[(wr * 64 + m * 16 + fr) * LD64 + ko]);
            }
            #pragma unroll
            for (int n = 0; n < 4; n++) {
                const s16x8 bh = ldfrag(&LBh[(wc * 64 + n * 16 + fr) * LD64 + ko]);
                const s16x8 bl = ldfrag(&LBl[(wc * 64 + n * 16 + fr) * LD64 + ko]);
                #pragma unroll
                for (int m = 0; m < 4; m++) {
                    acc[m][n] = __builtin_amdgcn_mfma_f32_16x16x32_bf16(afh[m], bh, acc[m][n], 0, 0, 0);
                    acc[m][n] = __builtin_amdgcn_mfma_f32_16x16x32_bf16(afl[m], bh, acc[m][n], 0, 0, 0);
                    acc[m][n] = __builtin_amdgcn_mfma_f32_16x16x32_bf16(afh[m], bl, acc[m][n], 0, 0, 0);
                }
            }
        }
    }

    #pragma unroll
    for (int m = 0; m < 4; m++)
        #pragma unroll
        for (int n = 0; n < 4; n++)
            #pragma unroll
            for (int r = 0; r < 4; r++) {
                const int row = bm0 + wr * 64 + m * 16 + fg * 4 + r;
                if (MODE >= 1 && row >= c) continue;
                const int col = bn0 + wc * 64 + n * 16 + fr;
                const size_t p = (size_t)((MODE >= 1 ? s : 0) + row) * N + col;
                if (EPI == 0) Cf[p] = acc[m][n][r];
                else          Cf[p] += acc[m][n][r];
            }
}

// ---------------- split-bf16 fused wg|wu GEMM, BK=64 (L1) ----------------
template<int MODE>
__global__ __launch_bounds__(256)
void k_mfma_sp_gu64(const short* __restrict__ Ah, const short* __restrict__ Alp,
                    const short* __restrict__ Bgh, const short* __restrict__ Bgl,
                    const short* __restrict__ Buh, const short* __restrict__ Bul,
                    float* __restrict__ Cg, short* __restrict__ Cuh, short* __restrict__ Cul,
                    const int* __restrict__ idx, const int* __restrict__ cnt,
                    const int* __restrict__ seg, int K)
{
    int c = T_, s = 0;
    const int bm0 = blockIdx.y * 128;
    const int bn0all = blockIdx.x * 128;
    if (MODE >= 1) {
        const int e = blockIdx.z;
        c = cnt[e];
        if (bm0 >= c) return;
        s = seg[e];
        Bgh += (size_t)e * I_ * K; Bgl += (size_t)e * I_ * K;
        Buh += (size_t)e * I_ * K; Bul += (size_t)e * I_ * K;
    }
    const int isU = (bn0all >= I_) ? 1 : 0;
    const int bn0 = bn0all - isU * I_;
    const short* Bh  = isU ? Buh : Bgh;
    const short* Blp = isU ? Bul : Bgl;

    __shared__ short LAh[128 * LD64];
    __shared__ short LAl[128 * LD64];
    __shared__ short LBh[128 * LD64];
    __shared__ short LBl[128 * LD64];
    const int tid  = threadIdx.x;
    const int lane = tid & 63, w = tid >> 6;
    const int wr = w >> 1, wc = w & 1;
    const int fr = lane & 15, fg = lane >> 4;
    const int srow = tid >> 1, sk = (tid & 1) * 32;

    int arow;
    if (MODE == 0) arow = bm0 + srow;
    else           arow = idx[s + min(bm0 + srow, c - 1)];
    const short* pah = Ah  + (size_t)arow * K + sk;
    const short* pal = Alp + (size_t)arow * K + sk;
    const short* pbh = Bh  + (size_t)(bn0 + srow) * K + sk;
    const short* pbl = Blp + (size_t)(bn0 + srow) * K + sk;

    f32x4 acc[4][4];
    #pragma unroll
    for (int m = 0; m < 4; m++)
        #pragma unroll
        for (int n = 0; n < 4; n++) acc[m][n] = (f32x4){0.f, 0.f, 0.f, 0.f};

    s16x8 rah[4], ral[4], rbh[4], rbl[4];
    #pragma unroll
    for (int q = 0; q < 4; q++) {
        rah[q] = *reinterpret_cast<const s16x8*>(pah + q * 8);
        ral[q] = *reinterpret_cast<const s16x8*>(pal + q * 8);
        rbh[q] = *reinterpret_cast<const s16x8*>(pbh + q * 8);
        rbl[q] = *reinterpret_cast<const s16x8*>(pbl + q * 8);
    }

    for (int k0 = 0; k0 < K; k0 += 64) {
        __syncthreads();
        #pragma unroll
        for (int q = 0; q < 4; q++) {
            *reinterpret_cast<s16x8*>(&LAh[srow * LD64 + sk + q * 8]) = rah[q];
            *reinterpret_cast<s16x8*>(&LAl[srow * LD64 + sk + q * 8]) = ral[q];
            *reinterpret_cast<s16x8*>(&LBh[srow * LD64 + sk + q * 8]) = rbh[q];
            *reinterpret_cast<s16x8*>(&LBl[srow * LD64 + sk + q * 8]) = rbl[q];
        }
        __syncthreads();
        if (k0 + 64 < K) {
            #pragma unroll
            for (int q = 0; q < 4; q++) {
                rah[q] = *reinterpret_cast<const s16x8*>(pah + k0 + 64 + q * 8);
                ral[q] = *reinterpret_cast<const s16x8*>(pal + k0 + 64 + q * 8);
                rbh[q] = *reinterpret_cast<const s16x8*>(pbh + k0 + 64 + q * 8);
                rbl[q] = *reinterpret_cast<const s16x8*>(pbl + k0 + 64 + q * 8);
            }
        }
        #pragma unroll
        for (int ks2 = 0; ks2 < 2; ks2++) {
            const int ko = ks2 * 32 + fg * 4;
            s16x8 afh[4], afl[4];
            #pragma unroll
            for (int m = 0; m < 4; m++) {
                afh[m] = ldfrag(&LAh[(wr * 64 + m * 16 + fr) * LD64 + ko]);
                afl[m] = ldfrag(&LAl[(wr * 64 + m * 16 + fr) * LD64 + ko]);
            }
            #pragma unroll
            for (int n = 0; n < 4; n++) {
                const s16x8 bh = ldfrag(&LBh[(wc * 64 + n * 16 + fr) * LD64 + ko]);
                const s16x8 bl = ldfrag(&LBl[(wc * 64 + n * 16 + fr) * LD64 + ko]);
                #pragma unroll
                for (int m = 0; m < 4; m++) {
                    acc[m][n] = __builtin_amdgcn_mfma_f32_16x16x32_bf16(afh[m], bh, acc[m][n], 0, 0, 0);
                    acc[m][n] = __builtin_amdgcn_mfma_f32_16x16x32_bf16(afl[m], bh, acc[m][n], 0, 0, 0);
                    acc[m][n] = __builtin_amdgcn_mfma_f32_16x16x32_bf16(afh[m], bl, acc[m][n], 0, 0, 0);
                }
            }
        }
    }

    #pragma unroll
    for (int m = 0; m < 4; m++)
        #pragma unroll
        for (int n = 0; n < 4; n++)
            #pragma unroll
            for (int r = 0; r < 4; r++) {
                const int row = bm0 + wr * 64 + m * 16 + fg * 4 + r;
                if (MODE >= 1 && row >= c) continue;
                const int col = bn0 + wc * 64 + n * 16 + fr;
                const size_t p = (size_t)((MODE >= 1 ? s : 0) + row) * I_ + col;
                if (!isU) {
                    Cg[p] = acc[m][n][r];
                } else {
                    const short hh = f2bf(acc[m][n][r]);
                    Cuh[p] = hh;
                    Cul[p] = f2bf(acc[m][n][r] - bf2f(hh));
                }
            }
}

extern "C" void kernel_launch(void* const* d_in, const int* in_sizes, int n_in,
                              void* d_out, int out_size, void* d_ws, size_t ws_size,
                              hipStream_t stream)
{
    const int*   ids    = (const int*)  d_in[0];
    const float* embed  = (const float*)d_in[1];
    const float* ln1_g  = (const float*)d_in[2];
    const float* ln1_b  = (const float*)d_in[3];
    const float* wq     = (const float*)d_in[4];
    const float* wk     = (const float*)d_in[5];
    const float* wv     = (const float*)d_in[6];
    const float* wo     = (const float*)d_in[7];
    const float* ln2_g  = (const float*)d_in[8];
    const float* ln2_b  = (const float*)d_in[9];
    const float* gate_w = (const float*)d_in[10];
    const float* exp_wg = (const float*)d_in[11];
    const float* exp_wu = (const float*)d_in[12];
    const float* exp_wd = (const float*)d_in[13];
    const float* sh_wg  = (const float*)d_in[14];
    const float* sh_wu  = (const float*)d_in[15];
    const float* sh_wd  = (const float*)d_in[16];
    const float* fn_g   = (const float*)d_in[17];
    const float* fn_b   = (const float*)d_in[18];
    const float* lm     = (const float*)d_in[19];
    float* out = (float*)d_out;

    float* x    = (float*)d_ws;                 // T*H
    float* h    = x + 2097152;                  // T*H
    float* qkvp = h + 2097152;                  // R1: [T][1536]; ebuf aliases
    float* ebuf = qkvp;
    float* gbuf = qkvp + 5242880;               // CAP*I f32
    float* gw   = gbuf + 5242880;               // T*8
    float* wl   = gw + (size_t)T_ * E_;         // CAP
    int*   idx  = (int*)(wl + CAP_);            // CAP
    int*   pos  = idx + CAP_;                   // T*2
    int*   cnt  = pos + 2 * T_;                 // 8
    int*   seg  = cnt + E_;                     // 8 (+pad)
    short* hhi  = (short*)(seg + 64);           // T*H
    short* hlo  = hhi + 2097152;
    short* hbf  = hlo + 2097152;
    short* obh  = hbf + 2097152;                // attn O hi
    short* obl  = obh + 2097152;                // attn O lo
    short* gbh  = obl + 2097152;                // CAP*I
    short* gbl  = gbh + 5242880;                // CAP*I
    short* wb   = gbl + 5242880;                // 56.6M shorts, phase-reused
    const size_t EW = (size_t)E_ * I_ * H_;     // 8,388,608

    short* qkvwh = wb;                          // [1536][1024] hi
    short* qkvwl = wb + 1572864;                // lo
    short* wowh  = wb + 3145728;                // [1024][1024] hi
    short* wowl  = wb + 4194304;                // lo
    short* khi_p = wb + 5242880;
    short* klo_p = khi_p + 524288;
    short* vth_p = klo_p + 524288;
    short* vtl_p = vth_p + 524288;

    k_embed<<<T_, 256, 0, stream>>>(ids, embed, x);

    for (int l = 0; l < L_; l++) {
        k_layernorm<2><<<T_, 256, 0, stream>>>(x, ln1_g + (size_t)l * H_, ln1_b + (size_t)l * H_, h, hhi, hlo);

        k_cvt_sp_t<<<dim3(16, 16), 256, 0, stream>>>(wq + (size_t)l * H_ * H_,   qkvwh,                qkvwl,                H_,  H_);
        k_cvt_sp_t<<<dim3(4, 16),  256, 0, stream>>>(wk + (size_t)l * H_ * 256,  qkvwh + 1024 * 1024,  qkvwl + 1024 * 1024,  256, H_);
        k_cvt_sp_t<<<dim3(4, 16),  256, 0, stream>>>(wv + (size_t)l * H_ * 256,  qkvwh + 1280 * 1024,  qkvwl + 1280 * 1024,  256, H_);
        k_cvt_sp_t<<<dim3(16, 16), 256, 0, stream>>>(wo + (size_t)l * H_ * H_,   wowh,                 wowl,                 H_,  H_);

        k_mfma_sp64<0, 0><<<dim3(QKVN / 128, 16, 1), 256, 0, stream>>>(
            hhi, hlo, qkvwh, qkvwl, qkvp, nullptr, nullptr, nullptr, QKVN, H_);

        k_rope_all<<<(T_ * 20 * 32) / 256, 256, 0, stream>>>(qkvp);

        k_cvt_kv<<<B_ * NKV_ * (S_ / 64), 256, 0, stream>>>(qkvp, khi_p, klo_p, vth_p, vtl_p);
        k_attn_mfma<<<dim3(S_ / 64, NH_, B_), 256, 0, stream>>>(qkvp, khi_p, klo_p, vth_p, vtl_p, obh, obl);

        k_mfma_sp64<0, 2><<<dim3(8, 16, 1), 256, 0, stream>>>(
            obh, obl, wowh, wowl, x, nullptr, nullptr, nullptr, H_, H_);

        if (l == 0)
            k_layernorm<2><<<T_, 256, 0, stream>>>(x, ln2_g + (size_t)l * H_, ln2_b + (size_t)l * H_, h, hhi, hlo);
        else
            k_layernorm<1><<<T_, 256, 0, stream>>>(x, ln2_g + (size_t)l * H_, ln2_b + (size_t)l * H_, h, hbf, nullptr);
        k_gate<<<T_, 64, 0, stream>>>(h, gate_w + (size_t)l * E_ * H_, gw);
        k_build<<<1, 512, 0, stream>>>(gw, idx, wl, pos, cnt, seg);

        const float* wg_l = exp_wg + (size_t)l * EW;
        const float* wu_l = exp_wu + (size_t)l * EW;
        const float* wd_l = exp_wd + (size_t)l * EW;
        const float* sg_l = sh_wg + (size_t)l * I_ * H_;
        const float* su_l = sh_wu + (size_t)l * I_ * H_;
        const float* sd_l = sh_wd + (size_t)l * H_ * I_;

        if (l == 0) {
            short* wgh = wb;            short* wgl = wb + EW;
            short* wuh = wb + 2 * EW;   short* wul = wb + 3 * EW;
            short* wdh = wb + 4 * EW;   short* wdl = wb + 5 * EW;
            short* sgh = wb + 6 * EW;   short* sgl = sgh + 1048576;
            short* suh = sgl + 1048576; short* sul = suh + 1048576;
            short* sdh = sul + 1048576; short* sdl = sdh + 1048576;

            k_cvt_sp<<<4096, 256, 0, stream>>>(wg_l, wgh, wgl, (int)(EW / 8));
            k_cvt_sp<<<4096, 256, 0, stream>>>(wu_l, wuh, wul, (int)(EW / 8));
            k_cvt_sp<<<4096, 256, 0, stream>>>(wd_l, wdh, wdl, (int)(EW / 8));
            k_cvt_sp<<<512,  256, 0, stream>>>(sg_l, sgh, sgl, 131072);
            k_cvt_sp<<<512,  256, 0, stream>>>(su_l, suh, sul, 131072);
            k_cvt_sp<<<512,  256, 0, stream>>>(sd_l, sdh, sdl, 131072);

            k_mfma_sp_gu64<0><<<dim3(16, 16, 1), 256, 0, stream>>>(
                hhi, hlo, sgh, sgl, suh, sul, gbuf, gbh, gbl, nullptr, nullptr, nullptr, H_);
            k_silu_sp<<<(T_ * I_) / 256, 256, 0, stream>>>(gbuf, gbh, gbl);
            k_mfma_sp64<0, 2><<<dim3(8, 16, 1), 256, 0, stream>>>(
                gbh, gbl, sdh, sdl, x, nullptr, nullptr, nullptr, H_, I_);
            k_mfma_sp_gu64<1><<<dim3(16, 16, E_), 256, 0, stream>>>(
                hhi, hlo, wgh, wgl, wuh, wul, gbuf, gbh, gbl, idx, cnt, seg, H_);
            k_silu_sp<<<(CAP_ * I_) / 256, 256, 0, stream>>>(gbuf, gbh, gbl);
            k_mfma_sp64<2, 0><<<dim3(8, 16, E_), 256, 0, stream>>>(
                gbh, gbl, wdh, wdl, ebuf, idx, cnt, seg, H_, I_);
        } else {
            short* wgb = wb;            short* wub = wb + EW;       short* wdb = wb + 2 * EW;
            short* sgb = wb + 3 * EW;   short* sub = sgb + 1048576; short* sdb = sub + 1048576;

            k_cvt<<<4096, 256, 0, stream>>>(wg_l, wgb, (int)(EW / 8));
            k_cvt<<<4096, 256, 0, stream>>>(wu_l, wub, (int)(EW / 8));
            k_cvt<<<4096, 256, 0, stream>>>(wd_l, wdb, (int)(EW / 8));
            k_cvt<<<512,  256, 0, stream>>>(sg_l, sgb, 131072);
            k_cvt<<<512,  256, 0, stream>>>(su_l, sub, 131072);
            k_cvt<<<512,  256, 0, stream>>>(sd_l, sdb, 131072);

            k_mfma_b_gu64<0><<<dim3(16, 16, 1), 256, 0, stream>>>(
                hbf, sgb, sub, gbuf, gbh, nullptr, nullptr, nullptr, H_);
            k_silu_b<<<(T_ * I_) / 256, 256, 0, stream>>>(gbuf, gbh);
            k_mfma_moe64<0, 2><<<dim3(8, 16, 1), 256, 0, stream>>>(
                gbh, sdb, x, nullptr, nullptr, nullptr, H_, I_);
            k_mfma_b_gu64<1><<<dim3(16, 16, E_), 256, 0, stream>>>(
                hbf, wgb, wub, gbuf, gbh, idx, cnt, seg, H_);
            k_silu_b<<<(CAP_ * I_) / 256, 256, 0, stream>>>(gbuf, gbh);
            k_mfma_moe64<2, 0><<<dim3(8, 16, E_), 256, 0, stream>>>(
                gbh, wdb, ebuf, idx, cnt, seg, H_, I_);
        }
        k_combine<<<(T_ * H_) / 256, 256, 0, stream>>>(x, ebuf, wl, pos);
    }

    k_layernorm<1><<<T_, 256, 0, stream>>>(x, fn_g, fn_b, h, hbf, nullptr);
    k_cvt<<<16000, 256, 0, stream>>>(lm, wb, 4096000);
    k_mfma_bt64<<<(T_ / 128) * (V_ / 128), 256, 0, stream>>>(hbf, wb, out, T_, V_, H_);
}